// Round 2
// baseline (5235.762 us; speedup 1.0000x reference)
//
#include <hip/hip_runtime.h>
#include <hip/hip_bf16.h>

typedef __hip_bfloat16 bf16;

#define Bb 2
#define Ll 2048
#define Cc 1024
#define Hh 16
#define Dd 64
// ln(50000)/32
#define INVFREQ_LN 0.3381180763f

// ---- load 8 consecutive elements as fp32 ----
__device__ inline void load8(const float* p, float* dst) {
    float4 a = *reinterpret_cast<const float4*>(p);
    float4 b = *reinterpret_cast<const float4*>(p + 4);
    dst[0] = a.x; dst[1] = a.y; dst[2] = a.z; dst[3] = a.w;
    dst[4] = b.x; dst[5] = b.y; dst[6] = b.z; dst[7] = b.w;
}
__device__ inline void load8(const bf16* p, float* dst) {
    float4 a = *reinterpret_cast<const float4*>(p);
    const bf16* e = reinterpret_cast<const bf16*>(&a);
    #pragma unroll
    for (int i = 0; i < 8; i++) dst[i] = __bfloat162float(e[i]);
}

// ---------------- GEMM: out = A[M,K] @ W[N,K]^T ----------------
// mode 0: scatter output to [B,H,L,D] bf16 (QKV projection), outb used
// mode 1: row-major [M,N] fp32 with fp32 bias, outf used
template <typename TA, typename TW>
__global__ __launch_bounds__(256) void gemm_bt(
    const TA* __restrict__ A, const TW* __restrict__ W,
    bf16* __restrict__ outb, float* __restrict__ outf,
    const float* __restrict__ bias,
    int M, int N, int K, int mode)
{
    __shared__ float As[64][33];
    __shared__ float Bs[64][33];
    const int tid = threadIdx.x;
    const int tx = tid & 15, ty = tid >> 4;
    const int m0 = blockIdx.y * 64, n0 = blockIdx.x * 64;
    const int lr = tid >> 2;          // 0..63
    const int lc = (tid & 3) * 8;     // 0,8,16,24

    float acc[4][4] = {};

    for (int k0 = 0; k0 < K; k0 += 32) {
        float tmp[8];
        load8(A + (size_t)(m0 + lr) * K + k0 + lc, tmp);
        #pragma unroll
        for (int i = 0; i < 8; i++) As[lr][lc + i] = tmp[i];
        load8(W + (size_t)(n0 + lr) * K + k0 + lc, tmp);
        #pragma unroll
        for (int i = 0; i < 8; i++) Bs[lr][lc + i] = tmp[i];
        __syncthreads();
        #pragma unroll
        for (int kk = 0; kk < 32; kk++) {
            float a[4], b[4];
            #pragma unroll
            for (int i = 0; i < 4; i++) a[i] = As[ty * 4 + i][kk];
            #pragma unroll
            for (int j = 0; j < 4; j++) b[j] = Bs[tx * 4 + j][kk];
            #pragma unroll
            for (int i = 0; i < 4; i++)
                #pragma unroll
                for (int j = 0; j < 4; j++)
                    acc[i][j] += a[i] * b[j];
        }
        __syncthreads();
    }

    #pragma unroll
    for (int i = 0; i < 4; i++) {
        int row = m0 + ty * 4 + i;
        #pragma unroll
        for (int j = 0; j < 4; j++) {
            int col = n0 + tx * 4 + j;
            float v = acc[i][j];
            if (mode == 0) {
                int b = row >> 11;          // /L
                int l = row & (Ll - 1);
                int h = col >> 6;           // /D
                int d = col & (Dd - 1);
                size_t idx = (((size_t)(b * Hh + h)) * Ll + l) * Dd + d;
                outb[idx] = __float2bfloat16(v);
            } else {
                if (bias) v += bias[col];
                outf[(size_t)row * N + col] = v;
            }
        }
    }
}

// ---------------- RoPE, in-place on [B,H,L,D] bf16 ----------------
__global__ __launch_bounds__(256) void rope(bf16* __restrict__ t)
{
    int idx = blockIdx.x * 256 + threadIdx.x;   // over B*H*L*(D/2)
    int j = idx & 31;
    int rest = idx >> 5;                        // (b*H+h)*L + l
    int l = rest & (Ll - 1);
    size_t base = (size_t)rest * Dd;
    float x1 = __bfloat162float(t[base + j]);
    float x2 = __bfloat162float(t[base + j + 32]);
    float freq = (float)l * __expf(-(float)j * INVFREQ_LN);
    float c = __cosf(freq), s = __sinf(freq);
    t[base + j]      = __float2bfloat16(x1 * c - x2 * s);
    t[base + j + 32] = __float2bfloat16(x2 * c + x1 * s);
}

// ---------------- Attention: one block per (b,h,l) query row ----------------
__global__ __launch_bounds__(256) void attn(
    const bf16* __restrict__ q, const bf16* __restrict__ k, const bf16* __restrict__ v,
    const int* __restrict__ mask, bf16* __restrict__ ctx)
{
    __shared__ float sq[Dd];
    __shared__ float sc[Ll];
    __shared__ float red[256];
    __shared__ float op[4][Dd];

    const int blk = blockIdx.x;          // (b*H+h)*L + l
    const int l   = blk & (Ll - 1);
    const int bh  = blk >> 11;
    const int b   = bh >> 4;
    const int h   = bh & (Hh - 1);
    const int tid = threadIdx.x;

    const bf16* qrow = q + ((size_t)bh * Ll + l) * Dd;
    const bf16* kb   = k + (size_t)bh * Ll * Dd;
    const bf16* vb   = v + (size_t)bh * Ll * Dd;
    const int* mrow  = mask + b * Ll;

    if (tid < Dd) sq[tid] = __bfloat162float(qrow[tid]);
    __syncthreads();

    // QK^T for 8 contiguous s per thread
    float scores[8];
    float m = -1e30f;
    #pragma unroll
    for (int r = 0; r < 8; r++) {
        int s = tid * 8 + r;
        const bf16* kr = kb + (size_t)s * Dd;
        float acc = 0.f;
        #pragma unroll
        for (int d0 = 0; d0 < Dd; d0 += 8) {
            float4 kv = *reinterpret_cast<const float4*>(kr + d0);
            const bf16* ke = reinterpret_cast<const bf16*>(&kv);
            #pragma unroll
            for (int i = 0; i < 8; i++) acc += sq[d0 + i] * __bfloat162float(ke[i]);
        }
        float scv = acc * 0.125f;
        if (mrow[s] == 0) scv = -1e30f;
        scores[r] = scv;
        m = fmaxf(m, scv);
    }

    // block max
    red[tid] = m;
    __syncthreads();
    for (int off = 128; off > 0; off >>= 1) {
        if (tid < off) red[tid] = fmaxf(red[tid], red[tid + off]);
        __syncthreads();
    }
    const float M = red[0];
    __syncthreads();

    // exp + block sum
    float lsum = 0.f;
    #pragma unroll
    for (int r = 0; r < 8; r++) {
        float p = __expf(scores[r] - M);
        sc[tid * 8 + r] = p;
        lsum += p;
    }
    red[tid] = lsum;
    __syncthreads();
    for (int off = 128; off > 0; off >>= 1) {
        if (tid < off) red[tid] += red[tid + off];
        __syncthreads();
    }
    const float inv = 1.0f / red[0];
    __syncthreads();

    // PV: 4 groups of 64 lanes, each covers 512 s values
    const int g = tid >> 6, d = tid & 63;
    float acc = 0.f;
    const int s0 = g * 512;
    #pragma unroll 4
    for (int s = s0; s < s0 + 512; s++) {
        acc += sc[s] * __bfloat162float(vb[(size_t)s * Dd + d]);
    }
    op[g][d] = acc;
    __syncthreads();

    if (tid < Dd) {
        float o = (op[0][tid] + op[1][tid] + op[2][tid] + op[3][tid]) * inv;
        ctx[((size_t)(b * Ll + l)) * Cc + h * Dd + tid] = __float2bfloat16(o);
    }
}

extern "C" void kernel_launch(void* const* d_in, const int* in_sizes, int n_in,
                              void* d_out, int out_size, void* d_ws, size_t ws_size,
                              hipStream_t stream) {
    const float* x    = (const float*)d_in[0];
    const int*   mask = (const int*)d_in[1];
    const float* Wq   = (const float*)d_in[2];
    const float* Wk   = (const float*)d_in[3];
    const float* Wv   = (const float*)d_in[4];
    const float* Wo   = (const float*)d_in[5];
    const float* bo   = (const float*)d_in[6];
    float* out = (float*)d_out;

    const size_t per = (size_t)Bb * Hh * Ll * Dd;   // 4 Mi elements
    bf16* qbuf = (bf16*)d_ws;
    bf16* kbuf = qbuf + per;
    bf16* vbuf = kbuf + per;
    bf16* ctx  = vbuf + per;

    const int M = Bb * Ll;   // 4096
    dim3 gGemm(Cc / 64, M / 64);   // 16 x 64

    gemm_bt<float, float><<<gGemm, 256, 0, stream>>>(x, Wq, qbuf, nullptr, nullptr, M, Cc, Cc, 0);
    gemm_bt<float, float><<<gGemm, 256, 0, stream>>>(x, Wk, kbuf, nullptr, nullptr, M, Cc, Cc, 0);
    gemm_bt<float, float><<<gGemm, 256, 0, stream>>>(x, Wv, vbuf, nullptr, nullptr, M, Cc, Cc, 0);

    int ropeThreads = Bb * Hh * Ll * (Dd / 2);      // 2 Mi
    rope<<<ropeThreads / 256, 256, 0, stream>>>(qbuf);
    rope<<<ropeThreads / 256, 256, 0, stream>>>(kbuf);

    attn<<<Bb * Hh * Ll, 256, 0, stream>>>(qbuf, kbuf, vbuf, mask, ctx);

    gemm_bt<bf16, float><<<gGemm, 256, 0, stream>>>(ctx, Wo, nullptr, out, bo, M, Cc, Cc, 1);
}

// Round 3
// 889.715 us; speedup vs baseline: 5.8848x; 5.8848x over previous
//
#include <hip/hip_runtime.h>
#include <hip/hip_bf16.h>

typedef __hip_bfloat16 bf16;
typedef short bf16x8 __attribute__((ext_vector_type(8)));
typedef float floatx4 __attribute__((ext_vector_type(4)));

#define Bb 2
#define Ll 2048
#define Cc 1024
#define Hh 16
#define Dd 64
// ln(50000)/32
#define INVFREQ_LN 0.3381180763f

// ---- load 8 consecutive elements as fp32 ----
__device__ inline void load8(const float* p, float* dst) {
    float4 a = *reinterpret_cast<const float4*>(p);
    float4 b = *reinterpret_cast<const float4*>(p + 4);
    dst[0] = a.x; dst[1] = a.y; dst[2] = a.z; dst[3] = a.w;
    dst[4] = b.x; dst[5] = b.y; dst[6] = b.z; dst[7] = b.w;
}
__device__ inline void load8(const bf16* p, float* dst) {
    float4 a = *reinterpret_cast<const float4*>(p);
    const bf16* e = reinterpret_cast<const bf16*>(&a);
    #pragma unroll
    for (int i = 0; i < 8; i++) dst[i] = __bfloat162float(e[i]);
}

// ---------------- GEMM: out = A[M,K] @ W[N,K]^T ----------------
// mode 0: scatter output to [B,H,L,D] bf16 (QKV projection), outb used
// mode 1: row-major [M,N] fp32 with fp32 bias, outf used
template <typename TA, typename TW>
__global__ __launch_bounds__(256) void gemm_bt(
    const TA* __restrict__ A, const TW* __restrict__ W,
    bf16* __restrict__ outb, float* __restrict__ outf,
    const float* __restrict__ bias,
    int M, int N, int K, int mode)
{
    __shared__ float As[64][33];
    __shared__ float Bs[64][33];
    const int tid = threadIdx.x;
    const int tx = tid & 15, ty = tid >> 4;
    const int m0 = blockIdx.y * 64, n0 = blockIdx.x * 64;
    const int lr = tid >> 2;          // 0..63
    const int lc = (tid & 3) * 8;     // 0,8,16,24

    float acc[4][4] = {};

    for (int k0 = 0; k0 < K; k0 += 32) {
        float tmp[8];
        load8(A + (size_t)(m0 + lr) * K + k0 + lc, tmp);
        #pragma unroll
        for (int i = 0; i < 8; i++) As[lr][lc + i] = tmp[i];
        load8(W + (size_t)(n0 + lr) * K + k0 + lc, tmp);
        #pragma unroll
        for (int i = 0; i < 8; i++) Bs[lr][lc + i] = tmp[i];
        __syncthreads();
        #pragma unroll
        for (int kk = 0; kk < 32; kk++) {
            float a[4], b[4];
            #pragma unroll
            for (int i = 0; i < 4; i++) a[i] = As[ty * 4 + i][kk];
            #pragma unroll
            for (int j = 0; j < 4; j++) b[j] = Bs[tx * 4 + j][kk];
            #pragma unroll
            for (int i = 0; i < 4; i++)
                #pragma unroll
                for (int j = 0; j < 4; j++)
                    acc[i][j] += a[i] * b[j];
        }
        __syncthreads();
    }

    #pragma unroll
    for (int i = 0; i < 4; i++) {
        int row = m0 + ty * 4 + i;
        #pragma unroll
        for (int j = 0; j < 4; j++) {
            int col = n0 + tx * 4 + j;
            float v = acc[i][j];
            if (mode == 0) {
                int b = row >> 11;          // /L
                int l = row & (Ll - 1);
                int h = col >> 6;           // /D
                int d = col & (Dd - 1);
                size_t idx = (((size_t)(b * Hh + h)) * Ll + l) * Dd + d;
                outb[idx] = __float2bfloat16(v);
            } else {
                if (bias) v += bias[col];
                outf[(size_t)row * N + col] = v;
            }
        }
    }
}

// ---------------- RoPE, in-place on [B,H,L,D] bf16 ----------------
__global__ __launch_bounds__(256) void rope(bf16* __restrict__ t)
{
    int idx = blockIdx.x * 256 + threadIdx.x;   // over B*H*L*(D/2)
    int j = idx & 31;
    int rest = idx >> 5;                        // (b*H+h)*L + l
    int l = rest & (Ll - 1);
    size_t base = (size_t)rest * Dd;
    float x1 = __bfloat162float(t[base + j]);
    float x2 = __bfloat162float(t[base + j + 32]);
    float freq = (float)l * __expf(-(float)j * INVFREQ_LN);
    float c = __cosf(freq), s = __sinf(freq);
    t[base + j]      = __float2bfloat16(x1 * c - x2 * s);
    t[base + j + 32] = __float2bfloat16(x2 * c + x1 * s);
}

// ---------------- Flash attention with MFMA ----------------
// Grid: (B*H) * (L/64) blocks. Block: 256 threads = 4 waves.
// Each block: one (b,h), 64-query tile (16 rows per wave).
// K-tiles of 64 keys staged in LDS; V staged transposed.
// All LDS row strides = 72 bf16 (144 B) -> 16B-aligned, conflict-free b128.
#define LSTR 72

__global__ __launch_bounds__(256) void attn_mfma(
    const bf16* __restrict__ q, const bf16* __restrict__ k, const bf16* __restrict__ v,
    const int* __restrict__ mask, bf16* __restrict__ ctx)
{
    __shared__ __align__(16) short Ks[64 * LSTR];
    __shared__ __align__(16) short Vt[64 * LSTR];
    __shared__ __align__(16) short Ps[4][16 * LSTR];
    __shared__ float msk[64];

    const int tid  = threadIdx.x;
    const int wave = tid >> 6;
    const int lane = tid & 63;
    const int l15  = lane & 15;
    const int quad = lane >> 4;

    const int bh = blockIdx.x >> 5;           // (b*H + h)
    const int q0 = (blockIdx.x & 31) << 6;    // query tile start
    const int b  = bh >> 4;
    const int h  = bh & (Hh - 1);

    const short* qb = (const short*)(q + (size_t)bh * Ll * Dd);
    const short* kb = (const short*)(k + (size_t)bh * Ll * Dd);
    const short* vb = (const short*)(v + (size_t)bh * Ll * Dd);
    const int* mrow = mask + b * Ll;

    // Q A-fragments: wave's 16 rows, A[m=lane&15][k=quad*8+j]
    const int qrow = q0 + wave * 16 + l15;
    bf16x8 qa0 = *(const bf16x8*)(qb + (size_t)qrow * Dd + quad * 8);
    bf16x8 qa1 = *(const bf16x8*)(qb + (size_t)qrow * Dd + 32 + quad * 8);

    floatx4 O[4];
    float m_r[4], l_r[4];
    #pragma unroll
    for (int nt = 0; nt < 4; nt++)
        #pragma unroll
        for (int r = 0; r < 4; r++) O[nt][r] = 0.f;
    #pragma unroll
    for (int r = 0; r < 4; r++) { m_r[r] = -1e30f; l_r[r] = 0.f; }

    for (int s0 = 0; s0 < Ll; s0 += 64) {
        __syncthreads();   // previous tile's LDS reads complete
        // ---- stage K tile [64 s][64 d], rows contiguous ----
        {
            const int n  = tid >> 3;           // 0..31
            const int c8 = (tid & 7) << 3;     // 0..56
            #pragma unroll
            for (int p = 0; p < 2; p++) {
                int nn = n + p * 32;
                *(bf16x8*)&Ks[nn * LSTR + c8] =
                    *(const bf16x8*)(kb + (size_t)(s0 + nn) * Dd + c8);
            }
        }
        // ---- stage V transposed: Vt[d][s] ----
        {
            const int s  = tid & 63;
            const int d0 = (tid >> 6) << 3;    // 0,8,16,24
            #pragma unroll
            for (int p = 0; p < 2; p++) {
                int dd = d0 + p * 32;
                bf16x8 tv = *(const bf16x8*)(vb + (size_t)(s0 + s) * Dd + dd);
                #pragma unroll
                for (int i = 0; i < 8; i++) Vt[(dd + i) * LSTR + s] = tv[i];
            }
        }
        if (tid < 64) msk[tid] = mrow[s0 + tid] ? 0.0f : -1e30f;
        __syncthreads();

        // ---- S = Q K^T via MFMA (C-layout: col=lane&15, row=quad*4+reg) ----
        floatx4 S[4];
        #pragma unroll
        for (int nt = 0; nt < 4; nt++) {
            const short* krow = &Ks[(nt * 16 + l15) * LSTR + quad * 8];
            bf16x8 kb0 = *(const bf16x8*)krow;
            bf16x8 kb1 = *(const bf16x8*)(krow + 32);
            floatx4 acc; acc[0] = acc[1] = acc[2] = acc[3] = 0.f;
            acc = __builtin_amdgcn_mfma_f32_16x16x32_bf16(qa0, kb0, acc, 0, 0, 0);
            acc = __builtin_amdgcn_mfma_f32_16x16x32_bf16(qa1, kb1, acc, 0, 0, 0);
            S[nt] = acc;
        }

        // ---- online softmax, per C-row (quad*4+r), reduce across 16 lanes ----
        #pragma unroll
        for (int r = 0; r < 4; r++) {
            float sv[4];
            #pragma unroll
            for (int nt = 0; nt < 4; nt++)
                sv[nt] = S[nt][r] * 0.125f + msk[nt * 16 + l15];
            float mx = fmaxf(fmaxf(sv[0], sv[1]), fmaxf(sv[2], sv[3]));
            mx = fmaxf(mx, __shfl_xor(mx, 1));
            mx = fmaxf(mx, __shfl_xor(mx, 2));
            mx = fmaxf(mx, __shfl_xor(mx, 4));
            mx = fmaxf(mx, __shfl_xor(mx, 8));
            float mnew  = fmaxf(m_r[r], mx);
            float alpha = __expf(m_r[r] - mnew);
            float psum = 0.f;
            #pragma unroll
            for (int nt = 0; nt < 4; nt++) {
                float p = __expf(sv[nt] - mnew);
                psum += p;
                __hip_bfloat16 hb = __float2bfloat16(p);
                Ps[wave][(quad * 4 + r) * LSTR + nt * 16 + l15] = *(short*)&hb;
            }
            psum += __shfl_xor(psum, 1);
            psum += __shfl_xor(psum, 2);
            psum += __shfl_xor(psum, 4);
            psum += __shfl_xor(psum, 8);
            l_r[r] = l_r[r] * alpha + psum;
            m_r[r] = mnew;
            #pragma unroll
            for (int nt = 0; nt < 4; nt++) O[nt][r] *= alpha;
        }
        __threadfence_block();   // wave's P writes -> visible to its own reads

        // ---- O += P V via MFMA; P read back in A-layout ----
        bf16x8 pa0 = *(const bf16x8*)&Ps[wave][l15 * LSTR + quad * 8];
        bf16x8 pa1 = *(const bf16x8*)&Ps[wave][l15 * LSTR + 32 + quad * 8];
        #pragma unroll
        for (int nt = 0; nt < 4; nt++) {
            const short* vrow = &Vt[(nt * 16 + l15) * LSTR + quad * 8];
            bf16x8 vb0 = *(const bf16x8*)vrow;
            bf16x8 vb1 = *(const bf16x8*)(vrow + 32);
            O[nt] = __builtin_amdgcn_mfma_f32_16x16x32_bf16(pa0, vb0, O[nt], 0, 0, 0);
            O[nt] = __builtin_amdgcn_mfma_f32_16x16x32_bf16(pa1, vb1, O[nt], 0, 0, 0);
        }
    }

    // ---- epilogue: normalize and write ctx [B, L, C] ----
    #pragma unroll
    for (int r = 0; r < 4; r++) {
        float inv = 1.0f / l_r[r];
        int row = q0 + wave * 16 + quad * 4 + r;
        size_t base = ((size_t)(b * Ll + row)) * Cc + h * Dd;
        #pragma unroll
        for (int nt = 0; nt < 4; nt++)
            ctx[base + nt * 16 + l15] = __float2bfloat16(O[nt][r] * inv);
    }
}

extern "C" void kernel_launch(void* const* d_in, const int* in_sizes, int n_in,
                              void* d_out, int out_size, void* d_ws, size_t ws_size,
                              hipStream_t stream) {
    const float* x    = (const float*)d_in[0];
    const int*   mask = (const int*)d_in[1];
    const float* Wq   = (const float*)d_in[2];
    const float* Wk   = (const float*)d_in[3];
    const float* Wv   = (const float*)d_in[4];
    const float* Wo   = (const float*)d_in[5];
    const float* bo   = (const float*)d_in[6];
    float* out = (float*)d_out;

    const size_t per = (size_t)Bb * Hh * Ll * Dd;   // 4 Mi elements
    bf16* qbuf = (bf16*)d_ws;
    bf16* kbuf = qbuf + per;
    bf16* vbuf = kbuf + per;
    bf16* ctx  = vbuf + per;

    const int M = Bb * Ll;   // 4096
    dim3 gGemm(Cc / 64, M / 64);   // 16 x 64

    gemm_bt<float, float><<<gGemm, 256, 0, stream>>>(x, Wq, qbuf, nullptr, nullptr, M, Cc, Cc, 0);
    gemm_bt<float, float><<<gGemm, 256, 0, stream>>>(x, Wk, kbuf, nullptr, nullptr, M, Cc, Cc, 0);
    gemm_bt<float, float><<<gGemm, 256, 0, stream>>>(x, Wv, vbuf, nullptr, nullptr, M, Cc, Cc, 0);

    int ropeThreads = Bb * Hh * Ll * (Dd / 2);      // 2 Mi
    rope<<<ropeThreads / 256, 256, 0, stream>>>(qbuf);
    rope<<<ropeThreads / 256, 256, 0, stream>>>(kbuf);

    attn_mfma<<<Bb * Hh * (Ll / 64), 256, 0, stream>>>(qbuf, kbuf, vbuf, mask, ctx);

    gemm_bt<bf16, float><<<gGemm, 256, 0, stream>>>(ctx, Wo, nullptr, out, bo, M, Cc, Cc, 1);
}

// Round 4
// 283.821 us; speedup vs baseline: 18.4474x; 3.1348x over previous
//
#include <hip/hip_runtime.h>
#include <hip/hip_bf16.h>

typedef __hip_bfloat16 bf16;
typedef short bf16x8 __attribute__((ext_vector_type(8)));
typedef float floatx4 __attribute__((ext_vector_type(4)));

#define Bb 2
#define Ll 2048
#define Cc 1024
#define Hh 16
#define Dd 64
// ln(50000)/32
#define INVFREQ_LN 0.3381180763f

#define GLD16(gp, lp) __builtin_amdgcn_global_load_lds( \
    (const __attribute__((address_space(1))) void*)(gp), \
    (__attribute__((address_space(3))) void*)(lp), 16, 0, 0)

// ---------------- convert fp32 inputs to bf16 workspace ----------------
__global__ __launch_bounds__(256) void convert_bf16(
    const float* __restrict__ x, const float* __restrict__ wq,
    const float* __restrict__ wk, const float* __restrict__ wv,
    const float* __restrict__ wo,
    bf16* __restrict__ xb, bf16* __restrict__ wqkv, bf16* __restrict__ wob)
{
    const int XN = (Bb * Ll * Cc) / 8;   // 524288
    const int WN = (Cc * Cc) / 8;        // 131072
    int i = blockIdx.x * 256 + threadIdx.x;
    const float* src; bf16* dst;
    if (i < XN)               { src = x  + (size_t)i * 8;                 dst = xb   + (size_t)i * 8; }
    else if (i < XN + WN)     { int j = i - XN;        src = wq + (size_t)j * 8; dst = wqkv + (size_t)j * 8; }
    else if (i < XN + 2*WN)   { int j = i - XN - WN;   src = wk + (size_t)j * 8; dst = wqkv + (size_t)Cc*Cc     + (size_t)j * 8; }
    else if (i < XN + 3*WN)   { int j = i - XN - 2*WN; src = wv + (size_t)j * 8; dst = wqkv + (size_t)Cc*Cc*2   + (size_t)j * 8; }
    else                      { int j = i - XN - 3*WN; src = wo + (size_t)j * 8; dst = wob  + (size_t)j * 8; }
    float4 a = *reinterpret_cast<const float4*>(src);
    float4 b = *reinterpret_cast<const float4*>(src + 4);
    float vv[8] = {a.x, a.y, a.z, a.w, b.x, b.y, b.z, b.w};
    bf16x8 o;
    #pragma unroll
    for (int t = 0; t < 8; t++) {
        bf16 h = __float2bfloat16(vv[t]);
        o[t] = *reinterpret_cast<short*>(&h);
    }
    *reinterpret_cast<bf16x8*>(dst) = o;
}

// ---------------- MFMA GEMM: C = A[M,K] . W[N,K]^T, all bf16 ----------------
// MODE 0: N=3072 fused QKV, scatter to q/k/v [B,H,L,D] bf16
// MODE 1: N=1024, out fp32 [M,N] + bias
template <int MODE>
__global__ __launch_bounds__(256) void gemm_mfma(
    const bf16* __restrict__ A, const bf16* __restrict__ W,
    bf16* __restrict__ qb, bf16* __restrict__ kb, bf16* __restrict__ vb,
    float* __restrict__ outf, const float* __restrict__ bias,
    int M, int N, int K)
{
    __shared__ __align__(16) short As[128 * 32];
    __shared__ __align__(16) short Bs[128 * 32];

    const int tid  = threadIdx.x;
    const int wave = tid >> 6;
    const int lane = tid & 63;
    const int l15  = lane & 15;
    const int quad = lane >> 4;
    const int wm   = wave >> 1;       // 2x2 wave grid
    const int wn   = wave & 1;
    const int m0   = blockIdx.y * 128;
    const int n0   = blockIdx.x * 128;

    const int ar = tid >> 2;          // 0..63 (row within 64-row chunk)
    const int ac = (tid & 3) * 8;     // 0,8,16,24

    floatx4 acc[4][4];
    #pragma unroll
    for (int mt = 0; mt < 4; mt++)
        #pragma unroll
        for (int nt = 0; nt < 4; nt++)
            #pragma unroll
            for (int r = 0; r < 4; r++) acc[mt][nt][r] = 0.f;

    for (int k0 = 0; k0 < K; k0 += 32) {
        __syncthreads();
        #pragma unroll
        for (int p = 0; p < 2; p++) {
            const bf16* gp = A + (size_t)(m0 + p * 64 + ar) * K + k0 + ac;
            GLD16(gp, &As[(p * 64 + ar) * 32 + ac]);
        }
        #pragma unroll
        for (int p = 0; p < 2; p++) {
            const bf16* gp = W + (size_t)(n0 + p * 64 + ar) * K + k0 + ac;
            GLD16(gp, &Bs[(p * 64 + ar) * 32 + ac]);
        }
        __syncthreads();

        bf16x8 af[4], bfr[4];
        #pragma unroll
        for (int mt = 0; mt < 4; mt++)
            af[mt] = *(const bf16x8*)&As[(wm * 64 + mt * 16 + l15) * 32 + quad * 8];
        #pragma unroll
        for (int nt = 0; nt < 4; nt++)
            bfr[nt] = *(const bf16x8*)&Bs[(wn * 64 + nt * 16 + l15) * 32 + quad * 8];
        #pragma unroll
        for (int mt = 0; mt < 4; mt++)
            #pragma unroll
            for (int nt = 0; nt < 4; nt++)
                acc[mt][nt] = __builtin_amdgcn_mfma_f32_16x16x32_bf16(
                    af[mt], bfr[nt], acc[mt][nt], 0, 0, 0);
    }

    // epilogue: C[row][col], row = m0+wm*64+mt*16+quad*4+r, col = n0+wn*64+nt*16+l15
    #pragma unroll
    for (int mt = 0; mt < 4; mt++) {
        #pragma unroll
        for (int r = 0; r < 4; r++) {
            int row = m0 + wm * 64 + mt * 16 + quad * 4 + r;
            #pragma unroll
            for (int nt = 0; nt < 4; nt++) {
                int col = n0 + wn * 64 + nt * 16 + l15;
                float v = acc[mt][nt][r];
                if (MODE == 0) {
                    int which = col >> 10;
                    int c = col & (Cc - 1);
                    int h = c >> 6;
                    int d = c & (Dd - 1);
                    int b = row >> 11;
                    int l = row & (Ll - 1);
                    bf16* dst = (which == 0) ? qb : (which == 1) ? kb : vb;
                    dst[(((size_t)(b * Hh + h)) * Ll + l) * Dd + d] = __float2bfloat16(v);
                } else {
                    outf[(size_t)row * N + col] = v + bias[col];
                }
            }
        }
    }
}

// ---------------- RoPE, in-place on [B,H,L,D] bf16 ----------------
__global__ __launch_bounds__(256) void rope(bf16* __restrict__ t)
{
    int idx = blockIdx.x * 256 + threadIdx.x;   // over B*H*L*(D/2)
    int j = idx & 31;
    int rest = idx >> 5;                        // (b*H+h)*L + l
    int l = rest & (Ll - 1);
    size_t base = (size_t)rest * Dd;
    float x1 = __bfloat162float(t[base + j]);
    float x2 = __bfloat162float(t[base + j + 32]);
    float freq = (float)l * __expf(-(float)j * INVFREQ_LN);
    float c = __cosf(freq), s = __sinf(freq);
    t[base + j]      = __float2bfloat16(x1 * c - x2 * s);
    t[base + j + 32] = __float2bfloat16(x2 * c + x1 * s);
}

// ---------------- Flash attention with MFMA ----------------
#define LSTR 72

__global__ __launch_bounds__(256) void attn_mfma(
    const bf16* __restrict__ q, const bf16* __restrict__ k, const bf16* __restrict__ v,
    const int* __restrict__ mask, bf16* __restrict__ ctx)
{
    __shared__ __align__(16) short Ks[64 * LSTR];
    __shared__ __align__(16) short Vt[64 * LSTR];
    __shared__ __align__(16) short Ps[4][16 * LSTR];
    __shared__ float msk[64];

    const int tid  = threadIdx.x;
    const int wave = tid >> 6;
    const int lane = tid & 63;
    const int l15  = lane & 15;
    const int quad = lane >> 4;

    const int bh = blockIdx.x >> 5;           // (b*H + h)
    const int q0 = (blockIdx.x & 31) << 6;    // query tile start
    const int b  = bh >> 4;
    const int h  = bh & (Hh - 1);

    const short* qb = (const short*)(q + (size_t)bh * Ll * Dd);
    const short* kb = (const short*)(k + (size_t)bh * Ll * Dd);
    const short* vb = (const short*)(v + (size_t)bh * Ll * Dd);
    const int* mrow = mask + b * Ll;

    const int qrow = q0 + wave * 16 + l15;
    bf16x8 qa0 = *(const bf16x8*)(qb + (size_t)qrow * Dd + quad * 8);
    bf16x8 qa1 = *(const bf16x8*)(qb + (size_t)qrow * Dd + 32 + quad * 8);

    floatx4 O[4];
    float m_r[4], l_r[4];
    #pragma unroll
    for (int nt = 0; nt < 4; nt++)
        #pragma unroll
        for (int r = 0; r < 4; r++) O[nt][r] = 0.f;
    #pragma unroll
    for (int r = 0; r < 4; r++) { m_r[r] = -1e30f; l_r[r] = 0.f; }

    for (int s0 = 0; s0 < Ll; s0 += 64) {
        __syncthreads();
        {
            const int n  = tid >> 3;
            const int c8 = (tid & 7) << 3;
            #pragma unroll
            for (int p = 0; p < 2; p++) {
                int nn = n + p * 32;
                *(bf16x8*)&Ks[nn * LSTR + c8] =
                    *(const bf16x8*)(kb + (size_t)(s0 + nn) * Dd + c8);
            }
        }
        {
            const int s  = tid & 63;
            const int d0 = (tid >> 6) << 3;
            #pragma unroll
            for (int p = 0; p < 2; p++) {
                int dd = d0 + p * 32;
                bf16x8 tv = *(const bf16x8*)(vb + (size_t)(s0 + s) * Dd + dd);
                #pragma unroll
                for (int i = 0; i < 8; i++) Vt[(dd + i) * LSTR + s] = tv[i];
            }
        }
        if (tid < 64) msk[tid] = mrow[s0 + tid] ? 0.0f : -1e30f;
        __syncthreads();

        floatx4 S[4];
        #pragma unroll
        for (int nt = 0; nt < 4; nt++) {
            const short* krow = &Ks[(nt * 16 + l15) * LSTR + quad * 8];
            bf16x8 kb0 = *(const bf16x8*)krow;
            bf16x8 kb1 = *(const bf16x8*)(krow + 32);
            floatx4 acc; acc[0] = acc[1] = acc[2] = acc[3] = 0.f;
            acc = __builtin_amdgcn_mfma_f32_16x16x32_bf16(qa0, kb0, acc, 0, 0, 0);
            acc = __builtin_amdgcn_mfma_f32_16x16x32_bf16(qa1, kb1, acc, 0, 0, 0);
            S[nt] = acc;
        }

        #pragma unroll
        for (int r = 0; r < 4; r++) {
            float sv[4];
            #pragma unroll
            for (int nt = 0; nt < 4; nt++)
                sv[nt] = S[nt][r] * 0.125f + msk[nt * 16 + l15];
            float mx = fmaxf(fmaxf(sv[0], sv[1]), fmaxf(sv[2], sv[3]));
            mx = fmaxf(mx, __shfl_xor(mx, 1));
            mx = fmaxf(mx, __shfl_xor(mx, 2));
            mx = fmaxf(mx, __shfl_xor(mx, 4));
            mx = fmaxf(mx, __shfl_xor(mx, 8));
            float mnew  = fmaxf(m_r[r], mx);
            float alpha = __expf(m_r[r] - mnew);
            float psum = 0.f;
            #pragma unroll
            for (int nt = 0; nt < 4; nt++) {
                float p = __expf(sv[nt] - mnew);
                psum += p;
                __hip_bfloat16 hb = __float2bfloat16(p);
                Ps[wave][(quad * 4 + r) * LSTR + nt * 16 + l15] = *(short*)&hb;
            }
            psum += __shfl_xor(psum, 1);
            psum += __shfl_xor(psum, 2);
            psum += __shfl_xor(psum, 4);
            psum += __shfl_xor(psum, 8);
            l_r[r] = l_r[r] * alpha + psum;
            m_r[r] = mnew;
            #pragma unroll
            for (int nt = 0; nt < 4; nt++) O[nt][r] *= alpha;
        }

        bf16x8 pa0 = *(const bf16x8*)&Ps[wave][l15 * LSTR + quad * 8];
        bf16x8 pa1 = *(const bf16x8*)&Ps[wave][l15 * LSTR + 32 + quad * 8];
        #pragma unroll
        for (int nt = 0; nt < 4; nt++) {
            const short* vrow = &Vt[(nt * 16 + l15) * LSTR + quad * 8];
            bf16x8 vb0 = *(const bf16x8*)vrow;
            bf16x8 vb1 = *(const bf16x8*)(vrow + 32);
            O[nt] = __builtin_amdgcn_mfma_f32_16x16x32_bf16(pa0, vb0, O[nt], 0, 0, 0);
            O[nt] = __builtin_amdgcn_mfma_f32_16x16x32_bf16(pa1, vb1, O[nt], 0, 0, 0);
        }
    }

    #pragma unroll
    for (int r = 0; r < 4; r++) {
        float inv = 1.0f / l_r[r];
        int row = q0 + wave * 16 + quad * 4 + r;
        size_t base = ((size_t)(b * Ll + row)) * Cc + h * Dd;
        #pragma unroll
        for (int nt = 0; nt < 4; nt++)
            ctx[base + nt * 16 + l15] = __float2bfloat16(O[nt][r] * inv);
    }
}

extern "C" void kernel_launch(void* const* d_in, const int* in_sizes, int n_in,
                              void* d_out, int out_size, void* d_ws, size_t ws_size,
                              hipStream_t stream) {
    const float* x    = (const float*)d_in[0];
    const int*   mask = (const int*)d_in[1];
    const float* Wq   = (const float*)d_in[2];
    const float* Wk   = (const float*)d_in[3];
    const float* Wv   = (const float*)d_in[4];
    const float* Wo   = (const float*)d_in[5];
    const float* bo   = (const float*)d_in[6];
    float* out = (float*)d_out;

    const size_t per = (size_t)Bb * Hh * Ll * Dd;   // 4 Mi elements
    bf16* qbuf = (bf16*)d_ws;
    bf16* kbuf = qbuf + per;
    bf16* vbuf = kbuf + per;
    bf16* xb   = vbuf + per;            // also used as ctx after x is dead
    bf16* wqkv = xb + per;              // [3072, 1024]
    bf16* wob  = wqkv + (size_t)3 * Cc * Cc;
    bf16* ctx  = xb;

    const int M = Bb * Ll;   // 4096

    // convert all fp32 inputs to bf16
    convert_bf16<<<(Bb*Ll*Cc/8 + 4*Cc*Cc/8) / 256, 256, 0, stream>>>(
        x, Wq, Wk, Wv, Wo, xb, wqkv, wob);

    // fused QKV projection: [4096, 3072]
    dim3 gQKV(3 * Cc / 128, M / 128);
    gemm_mfma<0><<<gQKV, 256, 0, stream>>>(xb, wqkv, qbuf, kbuf, vbuf,
                                           nullptr, nullptr, M, 3 * Cc, Cc);

    int ropeThreads = Bb * Hh * Ll * (Dd / 2);
    rope<<<ropeThreads / 256, 256, 0, stream>>>(qbuf);
    rope<<<ropeThreads / 256, 256, 0, stream>>>(kbuf);

    attn_mfma<<<Bb * Hh * (Ll / 64), 256, 0, stream>>>(qbuf, kbuf, vbuf, mask, ctx);

    // output projection: [4096, 1024] fp32 + bias
    dim3 gOut(Cc / 128, M / 128);
    gemm_mfma<1><<<gOut, 256, 0, stream>>>(ctx, wob, nullptr, nullptr, nullptr,
                                           out, bo, M, Cc, Cc);
}

// Round 6
// 226.666 us; speedup vs baseline: 23.0990x; 1.2522x over previous
//
#include <hip/hip_runtime.h>
#include <hip/hip_bf16.h>

typedef __hip_bfloat16 bf16;
typedef short bf16x8 __attribute__((ext_vector_type(8)));
typedef float floatx4 __attribute__((ext_vector_type(4)));

#define Bb 2
#define Ll 2048
#define Cc 1024
#define Hh 16
#define Dd 64
// ln(50000)/32
#define INVFREQ_LN 0.3381180763f
// 0.125 * log2(e): folded into Q at projection so softmax is exp2(S + msk)
#define QSCALE 0.18033688f

#define GLD16(gp, lp) __builtin_amdgcn_global_load_lds( \
    (const __attribute__((address_space(1))) void*)(gp), \
    (__attribute__((address_space(3))) void*)(lp), 16, 0, 0)

// ---------------- convert fp32 inputs to bf16 workspace ----------------
__global__ __launch_bounds__(256) void convert_bf16(
    const float* __restrict__ x, const float* __restrict__ wq,
    const float* __restrict__ wk, const float* __restrict__ wv,
    const float* __restrict__ wo,
    bf16* __restrict__ xb, bf16* __restrict__ wqkv, bf16* __restrict__ wob)
{
    const int XN = (Bb * Ll * Cc) / 8;   // 524288
    const int WN = (Cc * Cc) / 8;        // 131072
    int i = blockIdx.x * 256 + threadIdx.x;
    const float* src; bf16* dst;
    if (i < XN)               { src = x  + (size_t)i * 8;                 dst = xb   + (size_t)i * 8; }
    else if (i < XN + WN)     { int j = i - XN;        src = wq + (size_t)j * 8; dst = wqkv + (size_t)j * 8; }
    else if (i < XN + 2*WN)   { int j = i - XN - WN;   src = wk + (size_t)j * 8; dst = wqkv + (size_t)Cc*Cc     + (size_t)j * 8; }
    else if (i < XN + 3*WN)   { int j = i - XN - 2*WN; src = wv + (size_t)j * 8; dst = wqkv + (size_t)Cc*Cc*2   + (size_t)j * 8; }
    else                      { int j = i - XN - 3*WN; src = wo + (size_t)j * 8; dst = wob  + (size_t)j * 8; }
    float4 a = *reinterpret_cast<const float4*>(src);
    float4 b = *reinterpret_cast<const float4*>(src + 4);
    float vv[8] = {a.x, a.y, a.z, a.w, b.x, b.y, b.z, b.w};
    bf16x8 o;
    #pragma unroll
    for (int t = 0; t < 8; t++) {
        bf16 h = __float2bfloat16(vv[t]);
        o[t] = *reinterpret_cast<short*>(&h);
    }
    *reinterpret_cast<bf16x8*>(dst) = o;
}

// ---------------- MFMA GEMM: C = A[M,K] . W[N,K]^T, all bf16 ----------------
// MODE 0: N=3072 fused QKV. Epilogue: RoPE+scale on q/k -> [B,H,L,D];
//         V written TRANSPOSED -> [B,H,D,L].
// MODE 1: N=1024, out fp32 [M,N] + bias
template <int MODE>
__global__ __launch_bounds__(256) void gemm_mfma(
    const bf16* __restrict__ A, const bf16* __restrict__ W,
    bf16* __restrict__ qb, bf16* __restrict__ kb, bf16* __restrict__ vb,
    float* __restrict__ outf, const float* __restrict__ bias,
    int M, int N, int K)
{
    __shared__ __align__(16) short As[128 * 32];
    __shared__ __align__(16) short Bs[128 * 32];

    const int tid  = threadIdx.x;
    const int wave = tid >> 6;
    const int lane = tid & 63;
    const int l15  = lane & 15;
    const int quad = lane >> 4;
    const int wm   = wave >> 1;       // 2x2 wave grid
    const int wn   = wave & 1;
    const int m0   = blockIdx.y * 128;
    const int n0   = blockIdx.x * 128;

    const int ar = tid >> 2;          // 0..63 (row within 64-row chunk)
    const int ac = (tid & 3) * 8;     // 0,8,16,24

    floatx4 acc[4][4];
    #pragma unroll
    for (int mt = 0; mt < 4; mt++)
        #pragma unroll
        for (int nt = 0; nt < 4; nt++)
            #pragma unroll
            for (int r = 0; r < 4; r++) acc[mt][nt][r] = 0.f;

    for (int k0 = 0; k0 < K; k0 += 32) {
        __syncthreads();
        #pragma unroll
        for (int p = 0; p < 2; p++) {
            const bf16* gp = A + (size_t)(m0 + p * 64 + ar) * K + k0 + ac;
            GLD16(gp, &As[(p * 64 + ar) * 32 + ac]);
        }
        #pragma unroll
        for (int p = 0; p < 2; p++) {
            const bf16* gp = W + (size_t)(n0 + p * 64 + ar) * K + k0 + ac;
            GLD16(gp, &Bs[(p * 64 + ar) * 32 + ac]);
        }
        __syncthreads();

        bf16x8 af[4], bfr[4];
        #pragma unroll
        for (int mt = 0; mt < 4; mt++)
            af[mt] = *(const bf16x8*)&As[(wm * 64 + mt * 16 + l15) * 32 + quad * 8];
        #pragma unroll
        for (int nt = 0; nt < 4; nt++)
            bfr[nt] = *(const bf16x8*)&Bs[(wn * 64 + nt * 16 + l15) * 32 + quad * 8];
        #pragma unroll
        for (int mt = 0; mt < 4; mt++)
            #pragma unroll
            for (int nt = 0; nt < 4; nt++)
                acc[mt][nt] = __builtin_amdgcn_mfma_f32_16x16x32_bf16(
                    af[mt], bfr[nt], acc[mt][nt], 0, 0, 0);
    }

    // epilogue: C[row][col], row = m0+wm*64+mt*16+quad*4+r, col = n0+wn*64+nt*16+l15
    if (MODE == 1) {
        #pragma unroll
        for (int mt = 0; mt < 4; mt++)
            #pragma unroll
            for (int r = 0; r < 4; r++) {
                int row = m0 + wm * 64 + mt * 16 + quad * 4 + r;
                #pragma unroll
                for (int nt = 0; nt < 4; nt++) {
                    int col = n0 + wn * 64 + nt * 16 + l15;
                    outf[(size_t)row * N + col] = acc[mt][nt][r] + bias[col];
                }
            }
    } else {
        const int colbase = n0 + wn * 64;          // 64-aligned -> one (which,h)
        const int which   = colbase >> 10;         // 0=q, 1=k, 2=v
        const int hh      = (colbase & (Cc - 1)) >> 6;
        if (which == 2) {
            // V transposed: vb[((b*H+h)*D + d) * L + l]
            #pragma unroll
            for (int mt = 0; mt < 4; mt++)
                #pragma unroll
                for (int r = 0; r < 4; r++) {
                    int row = m0 + wm * 64 + mt * 16 + quad * 4 + r;
                    int b = row >> 11, l = row & (Ll - 1);
                    size_t base = (size_t)(b * Hh + hh) * Dd * Ll + l;
                    #pragma unroll
                    for (int nt = 0; nt < 4; nt++) {
                        int d = nt * 16 + l15;
                        vb[base + (size_t)d * Ll] = __float2bfloat16(acc[mt][nt][r]);
                    }
                }
        } else {
            bf16* dst = which ? kb : qb;
            const float qs = which ? 1.0f : QSCALE;
            const float base0 = __expf(-(float)l15 * INVFREQ_LN);
            const float base1 = __expf(-(float)(l15 + 16) * INVFREQ_LN);
            #pragma unroll
            for (int mt = 0; mt < 4; mt++)
                #pragma unroll
                for (int r = 0; r < 4; r++) {
                    int row = m0 + wm * 64 + mt * 16 + quad * 4 + r;
                    int b = row >> 11, l = row & (Ll - 1);
                    size_t rb = ((size_t)(b * Hh + hh) * Ll + l) * Dd;
                    #pragma unroll
                    for (int nt2 = 0; nt2 < 2; nt2++) {
                        float fr = (float)l * (nt2 ? base1 : base0);
                        float sn, cs;
                        __sincosf(fr, &sn, &cs);
                        float x1 = acc[mt][nt2][r];
                        float x2 = acc[mt][nt2 + 2][r];
                        dst[rb + nt2 * 16 + l15]      = __float2bfloat16((x1 * cs - x2 * sn) * qs);
                        dst[rb + nt2 * 16 + l15 + 32] = __float2bfloat16((x2 * cs + x1 * sn) * qs);
                    }
                }
        }
    }
}

// ---------------- Flash attention with MFMA (static softmax) ----------------
// q pre-scaled by 0.125*log2e and roped; k roped; v transposed [B,H,D,L].
// Grid: blockIdx.x = qt*32 + bh  (all q-tiles of a head -> same XCD).
#define LSTR 72

__global__ __launch_bounds__(256) void attn_mfma(
    const bf16* __restrict__ q, const bf16* __restrict__ k, const bf16* __restrict__ vt,
    const int* __restrict__ mask, bf16* __restrict__ ctx)
{
    __shared__ __align__(16) short Ks[64 * LSTR];
    __shared__ __align__(16) short Vs[64 * LSTR];
    __shared__ __align__(16) short Ps[4][16 * LSTR];
    __shared__ float msk[64];

    const int tid  = threadIdx.x;
    const int wave = tid >> 6;
    const int lane = tid & 63;
    const int l15  = lane & 15;
    const int quad = lane >> 4;

    const int bh = blockIdx.x & 31;           // (b*H + h) -> fixed XCD per head
    const int q0 = (blockIdx.x >> 5) << 6;    // query tile start
    const int b  = bh >> 4;
    const int h  = bh & (Hh - 1);

    const short* qb  = (const short*)(q  + (size_t)bh * Ll * Dd);
    const short* kb  = (const short*)(k  + (size_t)bh * Ll * Dd);
    const short* vtb = (const short*)(vt + (size_t)bh * Dd * Ll);
    const int* mrow = mask + b * Ll;

    const int qrow = q0 + wave * 16 + l15;
    bf16x8 qa0 = *(const bf16x8*)(qb + (size_t)qrow * Dd + quad * 8);
    bf16x8 qa1 = *(const bf16x8*)(qb + (size_t)qrow * Dd + 32 + quad * 8);

    floatx4 O[4];
    float l_r[4];
    #pragma unroll
    for (int nt = 0; nt < 4; nt++)
        #pragma unroll
        for (int r = 0; r < 4; r++) O[nt][r] = 0.f;
    #pragma unroll
    for (int r = 0; r < 4; r++) l_r[r] = 0.f;

    for (int s0 = 0; s0 < Ll; s0 += 64) {
        __syncthreads();
        // ---- stage K tile [64 s][64 d] ----
        {
            const int n  = tid >> 3;
            const int c8 = (tid & 7) << 3;
            #pragma unroll
            for (int p = 0; p < 2; p++) {
                int nn = n + p * 32;
                *(bf16x8*)&Ks[nn * LSTR + c8] =
                    *(const bf16x8*)(kb + (size_t)(s0 + nn) * Dd + c8);
            }
        }
        // ---- stage V tile [64 d][64 s] from transposed global ----
        {
            const int d   = tid >> 2;
            const int off = (tid & 3) << 4;
            #pragma unroll
            for (int p = 0; p < 2; p++) {
                int o = off + p * 8;
                *(bf16x8*)&Vs[d * LSTR + o] =
                    *(const bf16x8*)(vtb + (size_t)d * Ll + s0 + o);
            }
        }
        if (tid < 64) msk[tid] = mrow[s0 + tid] ? 0.0f : -1e30f;
        __syncthreads();

        // ---- S = Q K^T (C-layout: col=lane&15, row=quad*4+reg) ----
        floatx4 S[4];
        #pragma unroll
        for (int nt = 0; nt < 4; nt++) {
            const short* krow = &Ks[(nt * 16 + l15) * LSTR + quad * 8];
            bf16x8 kb0 = *(const bf16x8*)krow;
            bf16x8 kb1 = *(const bf16x8*)(krow + 32);
            floatx4 acc; acc[0] = acc[1] = acc[2] = acc[3] = 0.f;
            acc = __builtin_amdgcn_mfma_f32_16x16x32_bf16(qa0, kb0, acc, 0, 0, 0);
            acc = __builtin_amdgcn_mfma_f32_16x16x32_bf16(qa1, kb1, acc, 0, 0, 0);
            S[nt] = acc;
        }

        // ---- static softmax: p = 2^(S + msk); accumulate row-sum per lane ----
        #pragma unroll
        for (int r = 0; r < 4; r++) {
            #pragma unroll
            for (int nt = 0; nt < 4; nt++) {
                float p = exp2f(S[nt][r] + msk[nt * 16 + l15]);
                l_r[r] += p;
                __hip_bfloat16 hb = __float2bfloat16(p);
                Ps[wave][(quad * 4 + r) * LSTR + nt * 16 + l15] = *(short*)&hb;
            }
        }

        // ---- O += P V ----
        bf16x8 pa0 = *(const bf16x8*)&Ps[wave][l15 * LSTR + quad * 8];
        bf16x8 pa1 = *(const bf16x8*)&Ps[wave][l15 * LSTR + 32 + quad * 8];
        #pragma unroll
        for (int nt = 0; nt < 4; nt++) {
            const short* vrow = &Vs[(nt * 16 + l15) * LSTR + quad * 8];
            bf16x8 vb0 = *(const bf16x8*)vrow;
            bf16x8 vb1 = *(const bf16x8*)(vrow + 32);
            O[nt] = __builtin_amdgcn_mfma_f32_16x16x32_bf16(pa0, vb0, O[nt], 0, 0, 0);
            O[nt] = __builtin_amdgcn_mfma_f32_16x16x32_bf16(pa1, vb1, O[nt], 0, 0, 0);
        }
    }

    // ---- final row-sum reduction (16 lanes share a row) + write ----
    #pragma unroll
    for (int r = 0; r < 4; r++) {
        float l = l_r[r];
        l += __shfl_xor(l, 1);
        l += __shfl_xor(l, 2);
        l += __shfl_xor(l, 4);
        l += __shfl_xor(l, 8);
        float inv = 1.0f / l;
        int row = q0 + wave * 16 + quad * 4 + r;
        size_t base = ((size_t)(b * Ll + row)) * Cc + h * Dd;
        #pragma unroll
        for (int nt = 0; nt < 4; nt++)
            ctx[base + nt * 16 + l15] = __float2bfloat16(O[nt][r] * inv);
    }
}

extern "C" void kernel_launch(void* const* d_in, const int* in_sizes, int n_in,
                              void* d_out, int out_size, void* d_ws, size_t ws_size,
                              hipStream_t stream) {
    const float* x    = (const float*)d_in[0];
    const int*   mask = (const int*)d_in[1];
    const float* Wq   = (const float*)d_in[2];
    const float* Wk   = (const float*)d_in[3];
    const float* Wv   = (const float*)d_in[4];
    const float* Wo   = (const float*)d_in[5];
    const float* bo   = (const float*)d_in[6];
    float* out = (float*)d_out;

    const size_t per = (size_t)Bb * Hh * Ll * Dd;   // 4 Mi elements
    bf16* qbuf = (bf16*)d_ws;
    bf16* kbuf = qbuf + per;
    bf16* vbuf = kbuf + per;            // transposed [B,H,D,L]
    bf16* xb   = vbuf + per;            // also used as ctx after x is dead
    bf16* wqkv = xb + per;              // [3072, 1024]
    bf16* wob  = wqkv + (size_t)3 * Cc * Cc;
    bf16* ctx  = xb;

    const int M = Bb * Ll;   // 4096

    convert_bf16<<<(Bb*Ll*Cc/8 + 4*Cc*Cc/8) / 256, 256, 0, stream>>>(
        x, Wq, Wk, Wv, Wo, xb, wqkv, wob);

    // fused QKV projection + RoPE + Q-scale + V-transpose
    dim3 gQKV(3 * Cc / 128, M / 128);
    gemm_mfma<0><<<gQKV, 256, 0, stream>>>(xb, wqkv, qbuf, kbuf, vbuf,
                                           nullptr, nullptr, M, 3 * Cc, Cc);

    attn_mfma<<<Bb * Hh * (Ll / 64), 256, 0, stream>>>(qbuf, kbuf, vbuf, mask, ctx);

    // output projection: [4096, 1024] fp32 + bias
    dim3 gOut(Cc / 128, M / 128);
    gemm_mfma<1><<<gOut, 256, 0, stream>>>(ctx, wob, nullptr, nullptr, nullptr,
                                           out, bo, M, Cc, Cc);
}

// Round 7
// 220.691 us; speedup vs baseline: 23.7244x; 1.0271x over previous
//
#include <hip/hip_runtime.h>
#include <hip/hip_bf16.h>

typedef __hip_bfloat16 bf16;
typedef short bf16x8 __attribute__((ext_vector_type(8)));
typedef short bf16x4 __attribute__((ext_vector_type(4)));
typedef float floatx4 __attribute__((ext_vector_type(4)));

#define Bb 2
#define Ll 2048
#define Cc 1024
#define Hh 16
#define Dd 64
// ln(50000)/32
#define INVFREQ_LN 0.3381180763f
// 0.125 * log2(e): folded into Q at projection so softmax is exp2(S + msk)
#define QSCALE 0.18033688f

#define GLD16(gp, lp) __builtin_amdgcn_global_load_lds( \
    (const __attribute__((address_space(1))) void*)(gp), \
    (__attribute__((address_space(3))) void*)(lp), 16, 0, 0)

__device__ inline short f2bf(float f) {
    __hip_bfloat16 h = __float2bfloat16(f);
    return *reinterpret_cast<short*>(&h);
}

// ---------------- convert fp32 inputs to bf16 workspace ----------------
__global__ __launch_bounds__(256) void convert_bf16(
    const float* __restrict__ x, const float* __restrict__ wq,
    const float* __restrict__ wk, const float* __restrict__ wv,
    const float* __restrict__ wo,
    bf16* __restrict__ xb, bf16* __restrict__ wqkv, bf16* __restrict__ wob)
{
    const int XN = (Bb * Ll * Cc) / 8;   // 524288
    const int WN = (Cc * Cc) / 8;        // 131072
    int i = blockIdx.x * 256 + threadIdx.x;
    const float* src; bf16* dst;
    if (i < XN)               { src = x  + (size_t)i * 8;                 dst = xb   + (size_t)i * 8; }
    else if (i < XN + WN)     { int j = i - XN;        src = wq + (size_t)j * 8; dst = wqkv + (size_t)j * 8; }
    else if (i < XN + 2*WN)   { int j = i - XN - WN;   src = wk + (size_t)j * 8; dst = wqkv + (size_t)Cc*Cc     + (size_t)j * 8; }
    else if (i < XN + 3*WN)   { int j = i - XN - 2*WN; src = wv + (size_t)j * 8; dst = wqkv + (size_t)Cc*Cc*2   + (size_t)j * 8; }
    else                      { int j = i - XN - 3*WN; src = wo + (size_t)j * 8; dst = wob  + (size_t)j * 8; }
    float4 a = *reinterpret_cast<const float4*>(src);
    float4 b = *reinterpret_cast<const float4*>(src + 4);
    float vv[8] = {a.x, a.y, a.z, a.w, b.x, b.y, b.z, b.w};
    bf16x8 o;
    #pragma unroll
    for (int t = 0; t < 8; t++) o[t] = f2bf(vv[t]);
    *reinterpret_cast<bf16x8*>(dst) = o;
}

// ---------------- MFMA GEMM: C = A[M,K] . W[N,K]^T, all bf16 ----------------
// MODE 0: N=3072 fused QKV. Epilogue: RoPE+scale on q/k -> [B,H,L,D];
//         V written TRANSPOSED -> [B,H,D,L].
// MODE 1: N=1024, out fp32 [M,N] + bias
template <int MODE>
__global__ __launch_bounds__(256) void gemm_mfma(
    const bf16* __restrict__ A, const bf16* __restrict__ W,
    bf16* __restrict__ qb, bf16* __restrict__ kb, bf16* __restrict__ vb,
    float* __restrict__ outf, const float* __restrict__ bias,
    int M, int N, int K)
{
    __shared__ __align__(16) short As[128 * 32];
    __shared__ __align__(16) short Bs[128 * 32];

    const int tid  = threadIdx.x;
    const int wave = tid >> 6;
    const int lane = tid & 63;
    const int l15  = lane & 15;
    const int quad = lane >> 4;
    const int wm   = wave >> 1;       // 2x2 wave grid
    const int wn   = wave & 1;
    const int m0   = blockIdx.y * 128;
    const int n0   = blockIdx.x * 128;

    const int ar = tid >> 2;          // 0..63 (row within 64-row chunk)
    const int ac = (tid & 3) * 8;     // 0,8,16,24

    floatx4 acc[4][4];
    #pragma unroll
    for (int mt = 0; mt < 4; mt++)
        #pragma unroll
        for (int nt = 0; nt < 4; nt++)
            #pragma unroll
            for (int r = 0; r < 4; r++) acc[mt][nt][r] = 0.f;

    for (int k0 = 0; k0 < K; k0 += 32) {
        __syncthreads();
        #pragma unroll
        for (int p = 0; p < 2; p++) {
            const bf16* gp = A + (size_t)(m0 + p * 64 + ar) * K + k0 + ac;
            GLD16(gp, &As[(p * 64 + ar) * 32 + ac]);
        }
        #pragma unroll
        for (int p = 0; p < 2; p++) {
            const bf16* gp = W + (size_t)(n0 + p * 64 + ar) * K + k0 + ac;
            GLD16(gp, &Bs[(p * 64 + ar) * 32 + ac]);
        }
        __syncthreads();

        bf16x8 af[4], bfr[4];
        #pragma unroll
        for (int mt = 0; mt < 4; mt++)
            af[mt] = *(const bf16x8*)&As[(wm * 64 + mt * 16 + l15) * 32 + quad * 8];
        #pragma unroll
        for (int nt = 0; nt < 4; nt++)
            bfr[nt] = *(const bf16x8*)&Bs[(wn * 64 + nt * 16 + l15) * 32 + quad * 8];
        #pragma unroll
        for (int mt = 0; mt < 4; mt++)
            #pragma unroll
            for (int nt = 0; nt < 4; nt++)
                acc[mt][nt] = __builtin_amdgcn_mfma_f32_16x16x32_bf16(
                    af[mt], bfr[nt], acc[mt][nt], 0, 0, 0);
    }

    // epilogue: C[row][col], row = m0+wm*64+mt*16+quad*4+r, col = n0+wn*64+nt*16+l15
    if (MODE == 1) {
        #pragma unroll
        for (int mt = 0; mt < 4; mt++)
            #pragma unroll
            for (int r = 0; r < 4; r++) {
                int row = m0 + wm * 64 + mt * 16 + quad * 4 + r;
                #pragma unroll
                for (int nt = 0; nt < 4; nt++) {
                    int col = n0 + wn * 64 + nt * 16 + l15;
                    outf[(size_t)row * N + col] = acc[mt][nt][r] + bias[col];
                }
            }
    } else {
        const int colbase = n0 + wn * 64;          // 64-aligned -> one (which,h)
        const int which   = colbase >> 10;         // 0=q, 1=k, 2=v
        const int hh      = (colbase & (Cc - 1)) >> 6;
        if (which == 2) {
            // V transposed: vb[((b*H+h)*D + d) * L + l]
            #pragma unroll
            for (int mt = 0; mt < 4; mt++)
                #pragma unroll
                for (int r = 0; r < 4; r++) {
                    int row = m0 + wm * 64 + mt * 16 + quad * 4 + r;
                    int b = row >> 11, l = row & (Ll - 1);
                    size_t base = (size_t)(b * Hh + hh) * Dd * Ll + l;
                    #pragma unroll
                    for (int nt = 0; nt < 4; nt++) {
                        int d = nt * 16 + l15;
                        vb[base + (size_t)d * Ll] = __float2bfloat16(acc[mt][nt][r]);
                    }
                }
        } else {
            bf16* dst = which ? kb : qb;
            const float qs = which ? 1.0f : QSCALE;
            const float base0 = __expf(-(float)l15 * INVFREQ_LN);
            const float base1 = __expf(-(float)(l15 + 16) * INVFREQ_LN);
            #pragma unroll
            for (int mt = 0; mt < 4; mt++)
                #pragma unroll
                for (int r = 0; r < 4; r++) {
                    int row = m0 + wm * 64 + mt * 16 + quad * 4 + r;
                    int b = row >> 11, l = row & (Ll - 1);
                    size_t rb = ((size_t)(b * Hh + hh) * Ll + l) * Dd;
                    #pragma unroll
                    for (int nt2 = 0; nt2 < 2; nt2++) {
                        float fr = (float)l * (nt2 ? base1 : base0);
                        float sn, cs;
                        __sincosf(fr, &sn, &cs);
                        float x1 = acc[mt][nt2][r];
                        float x2 = acc[mt][nt2 + 2][r];
                        dst[rb + nt2 * 16 + l15]      = __float2bfloat16((x1 * cs - x2 * sn) * qs);
                        dst[rb + nt2 * 16 + l15 + 32] = __float2bfloat16((x2 * cs + x1 * sn) * qs);
                    }
                }
        }
    }
}

// ---------------- Flash attention with MFMA (S^T form, static softmax) ----------------
// q pre-scaled by 0.125*log2e and roped; k roped; v transposed [B,H,D,L].
// S^T = K.Q^T  -> lane holds S[q=l15][key=nt*16+quad*4+r]  (4 keys contiguous)
// P stored [q][key] row-major -> b64 packed writes; P re-read as B-fragment (b128).
// O^T = V^T.P^T -> lane holds O[q=l15][d=nt*16+quad*4+r]   (4 d contiguous -> b64 store)
#define LSTR 72

__global__ __launch_bounds__(256) void attn_mfma(
    const bf16* __restrict__ q, const bf16* __restrict__ k, const bf16* __restrict__ vt,
    const int* __restrict__ mask, bf16* __restrict__ ctx)
{
    __shared__ __align__(16) short Ks[64 * LSTR];
    __shared__ __align__(16) short Vs[64 * LSTR];
    __shared__ __align__(16) short Ps[4][16 * LSTR];
    __shared__ float msk[64];

    const int tid  = threadIdx.x;
    const int wave = tid >> 6;
    const int lane = tid & 63;
    const int l15  = lane & 15;
    const int quad = lane >> 4;

    const int bh = blockIdx.x & 31;           // (b*H + h) -> fixed XCD per head
    const int q0 = (blockIdx.x >> 5) << 6;    // query tile start
    const int b  = bh >> 4;
    const int h  = bh & (Hh - 1);

    const short* qb  = (const short*)(q  + (size_t)bh * Ll * Dd);
    const short* kb  = (const short*)(k  + (size_t)bh * Ll * Dd);
    const short* vtb = (const short*)(vt + (size_t)bh * Dd * Ll);
    const int* mrow = mask + b * Ll;

    // Q fragment (A- and B-layouts coincide per-lane): rows q0+wave*16+l15
    const int qrow = q0 + wave * 16 + l15;
    bf16x8 qa0 = *(const bf16x8*)(qb + (size_t)qrow * Dd + quad * 8);
    bf16x8 qa1 = *(const bf16x8*)(qb + (size_t)qrow * Dd + 32 + quad * 8);

    floatx4 O[4];
    float l_r = 0.f;
    #pragma unroll
    for (int nt = 0; nt < 4; nt++)
        #pragma unroll
        for (int r = 0; r < 4; r++) O[nt][r] = 0.f;

    for (int s0 = 0; s0 < Ll; s0 += 64) {
        __syncthreads();
        // ---- stage K tile [64 s][64 d] ----
        {
            const int n  = tid >> 3;
            const int c8 = (tid & 7) << 3;
            #pragma unroll
            for (int p = 0; p < 2; p++) {
                int nn = n + p * 32;
                *(bf16x8*)&Ks[nn * LSTR + c8] =
                    *(const bf16x8*)(kb + (size_t)(s0 + nn) * Dd + c8);
            }
        }
        // ---- stage V tile [64 d][64 s] from transposed global ----
        {
            const int d   = tid >> 2;
            const int off = (tid & 3) << 4;
            #pragma unroll
            for (int p = 0; p < 2; p++) {
                int o = off + p * 8;
                *(bf16x8*)&Vs[d * LSTR + o] =
                    *(const bf16x8*)(vtb + (size_t)d * Ll + s0 + o);
            }
        }
        if (tid < 64) msk[tid] = mrow[s0 + tid] ? 0.0f : -1e30f;
        __syncthreads();

        // ---- S^T = K Q^T: lane holds S[q=l15][key=nt*16+quad*4+r] ----
        floatx4 S[4];
        #pragma unroll
        for (int nt = 0; nt < 4; nt++) {
            const short* krow = &Ks[(nt * 16 + l15) * LSTR + quad * 8];
            bf16x8 ka0 = *(const bf16x8*)krow;
            bf16x8 ka1 = *(const bf16x8*)(krow + 32);
            floatx4 acc; acc[0] = acc[1] = acc[2] = acc[3] = 0.f;
            acc = __builtin_amdgcn_mfma_f32_16x16x32_bf16(ka0, qa0, acc, 0, 0, 0);
            acc = __builtin_amdgcn_mfma_f32_16x16x32_bf16(ka1, qa1, acc, 0, 0, 0);
            S[nt] = acc;
        }

        // ---- static softmax: p = 2^(S + msk); packed b64 P-writes ----
        #pragma unroll
        for (int nt = 0; nt < 4; nt++) {
            bf16x4 pw;
            #pragma unroll
            for (int r = 0; r < 4; r++) {
                float p = exp2f(S[nt][r] + msk[nt * 16 + quad * 4 + r]);
                l_r += p;
                pw[r] = f2bf(p);
            }
            *(bf16x4*)&Ps[wave][l15 * LSTR + nt * 16 + quad * 4] = pw;
        }

        // ---- O^T += V^T P^T: A=Vs rows (d), B=Ps rows (q) ----
        bf16x8 pb0 = *(const bf16x8*)&Ps[wave][l15 * LSTR + quad * 8];
        bf16x8 pb1 = *(const bf16x8*)&Ps[wave][l15 * LSTR + 32 + quad * 8];
        #pragma unroll
        for (int nt = 0; nt < 4; nt++) {
            const short* vrow = &Vs[(nt * 16 + l15) * LSTR + quad * 8];
            bf16x8 va0 = *(const bf16x8*)vrow;
            bf16x8 va1 = *(const bf16x8*)(vrow + 32);
            O[nt] = __builtin_amdgcn_mfma_f32_16x16x32_bf16(va0, pb0, O[nt], 0, 0, 0);
            O[nt] = __builtin_amdgcn_mfma_f32_16x16x32_bf16(va1, pb1, O[nt], 0, 0, 0);
        }
    }

    // ---- row-sum: lanes with same l15 across quads hold the same q ----
    float l = l_r;
    l += __shfl_xor(l, 16);
    l += __shfl_xor(l, 32);
    const float inv = 1.0f / l;

    // ---- write ctx: lane holds O[q=l15][d=nt*16+quad*4+r] -> b64 stores ----
    {
        int row = q0 + wave * 16 + l15;
        short* cp = (short*)ctx + ((size_t)(b * Ll + row)) * Cc + h * Dd;
        #pragma unroll
        for (int nt = 0; nt < 4; nt++) {
            bf16x4 ov;
            #pragma unroll
            for (int r = 0; r < 4; r++) ov[r] = f2bf(O[nt][r] * inv);
            *(bf16x4*)&cp[nt * 16 + quad * 4] = ov;
        }
    }
}

extern "C" void kernel_launch(void* const* d_in, const int* in_sizes, int n_in,
                              void* d_out, int out_size, void* d_ws, size_t ws_size,
                              hipStream_t stream) {
    const float* x    = (const float*)d_in[0];
    const int*   mask = (const int*)d_in[1];
    const float* Wq   = (const float*)d_in[2];
    const float* Wk   = (const float*)d_in[3];
    const float* Wv   = (const float*)d_in[4];
    const float* Wo   = (const float*)d_in[5];
    const float* bo   = (const float*)d_in[6];
    float* out = (float*)d_out;

    const size_t per = (size_t)Bb * Hh * Ll * Dd;   // 4 Mi elements
    bf16* qbuf = (bf16*)d_ws;
    bf16* kbuf = qbuf + per;
    bf16* vbuf = kbuf + per;            // transposed [B,H,D,L]
    bf16* xb   = vbuf + per;            // also used as ctx after x is dead
    bf16* wqkv = xb + per;              // [3072, 1024]
    bf16* wob  = wqkv + (size_t)3 * Cc * Cc;
    bf16* ctx  = xb;

    const int M = Bb * Ll;   // 4096

    convert_bf16<<<(Bb*Ll*Cc/8 + 4*Cc*Cc/8) / 256, 256, 0, stream>>>(
        x, Wq, Wk, Wv, Wo, xb, wqkv, wob);

    // fused QKV projection + RoPE + Q-scale + V-transpose
    dim3 gQKV(3 * Cc / 128, M / 128);
    gemm_mfma<0><<<gQKV, 256, 0, stream>>>(xb, wqkv, qbuf, kbuf, vbuf,
                                           nullptr, nullptr, M, 3 * Cc, Cc);

    attn_mfma<<<Bb * Hh * (Ll / 64), 256, 0, stream>>>(qbuf, kbuf, vbuf, mask, ctx);

    // output projection: [4096, 1024] fp32 + bias
    dim3 gOut(Cc / 128, M / 128);
    gemm_mfma<1><<<gOut, 256, 0, stream>>>(ctx, wob, nullptr, nullptr, nullptr,
                                           out, bo, M, Cc, Cc);
}

// Round 8
// 213.598 us; speedup vs baseline: 24.5123x; 1.0332x over previous
//
#include <hip/hip_runtime.h>
#include <hip/hip_bf16.h>

typedef __hip_bfloat16 bf16;
typedef short bf16x8 __attribute__((ext_vector_type(8)));
typedef short bf16x4 __attribute__((ext_vector_type(4)));
typedef float floatx4 __attribute__((ext_vector_type(4)));

#define Bb 2
#define Ll 2048
#define Cc 1024
#define Hh 16
#define Dd 64
// ln(50000)/32
#define INVFREQ_LN 0.3381180763f
// plain 1/sqrt(D) folded into Q; softmax uses __expf (natural)
#define QSCALE 0.125f

#define GLD16(gp, lp) __builtin_amdgcn_global_load_lds( \
    (const __attribute__((address_space(1))) void*)(gp), \
    (__attribute__((address_space(3))) void*)(lp), 16, 0, 0)

__device__ inline short f2bf(float f) {
    __hip_bfloat16 h = __float2bfloat16(f);
    return *reinterpret_cast<short*>(&h);
}
// fast round-to-nearest bf16 (ties-away); fine for finite positive values
__device__ inline short f2bf_rn(float f) {
    return (short)((__float_as_uint(f) + 0x8000u) >> 16);
}

// ---------------- convert fp32 inputs to bf16 workspace ----------------
__global__ __launch_bounds__(256) void convert_bf16(
    const float* __restrict__ x, const float* __restrict__ wq,
    const float* __restrict__ wk, const float* __restrict__ wv,
    const float* __restrict__ wo,
    bf16* __restrict__ xb, bf16* __restrict__ wqkv, bf16* __restrict__ wob)
{
    const int XN = (Bb * Ll * Cc) / 8;   // 524288
    const int WN = (Cc * Cc) / 8;        // 131072
    int i = blockIdx.x * 256 + threadIdx.x;
    const float* src; bf16* dst;
    if (i < XN)               { src = x  + (size_t)i * 8;                 dst = xb   + (size_t)i * 8; }
    else if (i < XN + WN)     { int j = i - XN;        src = wq + (size_t)j * 8; dst = wqkv + (size_t)j * 8; }
    else if (i < XN + 2*WN)   { int j = i - XN - WN;   src = wk + (size_t)j * 8; dst = wqkv + (size_t)Cc*Cc     + (size_t)j * 8; }
    else if (i < XN + 3*WN)   { int j = i - XN - 2*WN; src = wv + (size_t)j * 8; dst = wqkv + (size_t)Cc*Cc*2   + (size_t)j * 8; }
    else                      { int j = i - XN - 3*WN; src = wo + (size_t)j * 8; dst = wob  + (size_t)j * 8; }
    float4 a = *reinterpret_cast<const float4*>(src);
    float4 b = *reinterpret_cast<const float4*>(src + 4);
    float vv[8] = {a.x, a.y, a.z, a.w, b.x, b.y, b.z, b.w};
    bf16x8 o;
    #pragma unroll
    for (int t = 0; t < 8; t++) o[t] = f2bf(vv[t]);
    *reinterpret_cast<bf16x8*>(dst) = o;
}

// ---------------- MFMA GEMM: C = A[M,K] . W[N,K]^T, all bf16 ----------------
// MODE 0: N=3072 fused QKV. Epilogue: RoPE+scale on q/k -> [B,H,L,D];
//         V written TRANSPOSED -> [B,H,D,L].
// MODE 1: N=1024, out fp32 [M,N] + bias
template <int MODE>
__global__ __launch_bounds__(256) void gemm_mfma(
    const bf16* __restrict__ A, const bf16* __restrict__ W,
    bf16* __restrict__ qb, bf16* __restrict__ kb, bf16* __restrict__ vb,
    float* __restrict__ outf, const float* __restrict__ bias,
    int M, int N, int K)
{
    __shared__ __align__(16) short As[128 * 32];
    __shared__ __align__(16) short Bs[128 * 32];

    const int tid  = threadIdx.x;
    const int wave = tid >> 6;
    const int lane = tid & 63;
    const int l15  = lane & 15;
    const int quad = lane >> 4;
    const int wm   = wave >> 1;       // 2x2 wave grid
    const int wn   = wave & 1;
    const int m0   = blockIdx.y * 128;
    const int n0   = blockIdx.x * 128;

    const int ar = tid >> 2;          // 0..63 (row within 64-row chunk)
    const int ac = (tid & 3) * 8;     // 0,8,16,24

    floatx4 acc[4][4];
    #pragma unroll
    for (int mt = 0; mt < 4; mt++)
        #pragma unroll
        for (int nt = 0; nt < 4; nt++)
            #pragma unroll
            for (int r = 0; r < 4; r++) acc[mt][nt][r] = 0.f;

    for (int k0 = 0; k0 < K; k0 += 32) {
        __syncthreads();
        #pragma unroll
        for (int p = 0; p < 2; p++) {
            const bf16* gp = A + (size_t)(m0 + p * 64 + ar) * K + k0 + ac;
            GLD16(gp, &As[(p * 64 + ar) * 32 + ac]);
        }
        #pragma unroll
        for (int p = 0; p < 2; p++) {
            const bf16* gp = W + (size_t)(n0 + p * 64 + ar) * K + k0 + ac;
            GLD16(gp, &Bs[(p * 64 + ar) * 32 + ac]);
        }
        __syncthreads();

        bf16x8 af[4], bfr[4];
        #pragma unroll
        for (int mt = 0; mt < 4; mt++)
            af[mt] = *(const bf16x8*)&As[(wm * 64 + mt * 16 + l15) * 32 + quad * 8];
        #pragma unroll
        for (int nt = 0; nt < 4; nt++)
            bfr[nt] = *(const bf16x8*)&Bs[(wn * 64 + nt * 16 + l15) * 32 + quad * 8];
        #pragma unroll
        for (int mt = 0; mt < 4; mt++)
            #pragma unroll
            for (int nt = 0; nt < 4; nt++)
                acc[mt][nt] = __builtin_amdgcn_mfma_f32_16x16x32_bf16(
                    af[mt], bfr[nt], acc[mt][nt], 0, 0, 0);
    }

    // epilogue: C[row][col], row = m0+wm*64+mt*16+quad*4+r, col = n0+wn*64+nt*16+l15
    if (MODE == 1) {
        #pragma unroll
        for (int mt = 0; mt < 4; mt++)
            #pragma unroll
            for (int r = 0; r < 4; r++) {
                int row = m0 + wm * 64 + mt * 16 + quad * 4 + r;
                #pragma unroll
                for (int nt = 0; nt < 4; nt++) {
                    int col = n0 + wn * 64 + nt * 16 + l15;
                    outf[(size_t)row * N + col] = acc[mt][nt][r] + bias[col];
                }
            }
    } else {
        const int colbase = n0 + wn * 64;          // 64-aligned -> one (which,h)
        const int which   = colbase >> 10;         // 0=q, 1=k, 2=v
        const int hh      = (colbase & (Cc - 1)) >> 6;
        if (which == 2) {
            // V transposed: vb[((b*H+h)*D + d) * L + l]
            #pragma unroll
            for (int mt = 0; mt < 4; mt++)
                #pragma unroll
                for (int r = 0; r < 4; r++) {
                    int row = m0 + wm * 64 + mt * 16 + quad * 4 + r;
                    int b = row >> 11, l = row & (Ll - 1);
                    size_t base = (size_t)(b * Hh + hh) * Dd * Ll + l;
                    #pragma unroll
                    for (int nt = 0; nt < 4; nt++) {
                        int d = nt * 16 + l15;
                        vb[base + (size_t)d * Ll] = __float2bfloat16(acc[mt][nt][r]);
                    }
                }
        } else {
            bf16* dst = which ? kb : qb;
            const float qs = which ? 1.0f : QSCALE;
            const float base0 = __expf(-(float)l15 * INVFREQ_LN);
            const float base1 = __expf(-(float)(l15 + 16) * INVFREQ_LN);
            #pragma unroll
            for (int mt = 0; mt < 4; mt++)
                #pragma unroll
                for (int r = 0; r < 4; r++) {
                    int row = m0 + wm * 64 + mt * 16 + quad * 4 + r;
                    int b = row >> 11, l = row & (Ll - 1);
                    size_t rb = ((size_t)(b * Hh + hh) * Ll + l) * Dd;
                    #pragma unroll
                    for (int nt2 = 0; nt2 < 2; nt2++) {
                        float fr = (float)l * (nt2 ? base1 : base0);
                        float sn, cs;
                        __sincosf(fr, &sn, &cs);
                        float x1 = acc[mt][nt2][r];
                        float x2 = acc[mt][nt2 + 2][r];
                        dst[rb + nt2 * 16 + l15]      = __float2bfloat16((x1 * cs - x2 * sn) * qs);
                        dst[rb + nt2 * 16 + l15 + 32] = __float2bfloat16((x2 * cs + x1 * sn) * qs);
                    }
                }
        }
    }
}

// ---------------- Flash attention with MFMA (S^T form, static softmax) ----------------
// q pre-scaled by 0.125 and roped; k roped; v transposed [B,H,D,L].
// Block = 128 queries (4 waves x 2 q-subtiles of 16); K/V frags amortized over subtiles.
// S^T = K.Q^T  -> lane holds S[q=l15][key=nt*16+quad*4+r]
// P stored [q][key] row-major; re-read as B-fragment (b128).
// O^T = V^T.P^T -> lane holds O[q=l15][d=nt*16+quad*4+r]
#define LSTR 72

__global__ __launch_bounds__(256) void attn_mfma(
    const bf16* __restrict__ q, const bf16* __restrict__ k, const bf16* __restrict__ vt,
    const int* __restrict__ mask, bf16* __restrict__ ctx)
{
    __shared__ __align__(16) short Ks[64 * LSTR];
    __shared__ __align__(16) short Vs[64 * LSTR];
    __shared__ __align__(16) short Ps[8][16 * LSTR];
    __shared__ float msk[64];

    const int tid  = threadIdx.x;
    const int wave = tid >> 6;
    const int lane = tid & 63;
    const int l15  = lane & 15;
    const int quad = lane >> 4;

    const int bh = blockIdx.x & 31;           // (b*H + h) -> fixed XCD per head
    const int q0 = (blockIdx.x >> 5) << 7;    // 128-query tile start
    const int b  = bh >> 4;
    const int h  = bh & (Hh - 1);

    const short* qb  = (const short*)(q  + (size_t)bh * Ll * Dd);
    const short* kb  = (const short*)(k  + (size_t)bh * Ll * Dd);
    const short* vtb = (const short*)(vt + (size_t)bh * Dd * Ll);
    const int* mrow = mask + b * Ll;

    // Q fragments for 2 subtiles
    bf16x8 qa[2][2];
    #pragma unroll
    for (int qt = 0; qt < 2; qt++) {
        int qrow = q0 + qt * 64 + wave * 16 + l15;
        qa[qt][0] = *(const bf16x8*)(qb + (size_t)qrow * Dd + quad * 8);
        qa[qt][1] = *(const bf16x8*)(qb + (size_t)qrow * Dd + 32 + quad * 8);
    }

    floatx4 O[2][4];
    float l_r[2] = {0.f, 0.f};
    #pragma unroll
    for (int qt = 0; qt < 2; qt++)
        #pragma unroll
        for (int nt = 0; nt < 4; nt++)
            #pragma unroll
            for (int r = 0; r < 4; r++) O[qt][nt][r] = 0.f;

    for (int s0 = 0; s0 < Ll; s0 += 64) {
        __syncthreads();
        // ---- stage K tile [64 s][64 d] ----
        {
            const int n  = tid >> 3;
            const int c8 = (tid & 7) << 3;
            #pragma unroll
            for (int p = 0; p < 2; p++) {
                int nn = n + p * 32;
                *(bf16x8*)&Ks[nn * LSTR + c8] =
                    *(const bf16x8*)(kb + (size_t)(s0 + nn) * Dd + c8);
            }
        }
        // ---- stage V tile [64 d][64 s] from transposed global ----
        {
            const int d   = tid >> 2;
            const int off = (tid & 3) << 4;
            #pragma unroll
            for (int p = 0; p < 2; p++) {
                int o = off + p * 8;
                *(bf16x8*)&Vs[d * LSTR + o] =
                    *(const bf16x8*)(vtb + (size_t)d * Ll + s0 + o);
            }
        }
        if (tid < 64) msk[tid] = mrow[s0 + tid] ? 0.0f : -1e30f;
        __syncthreads();

        // ---- S^T = K Q^T; K-frag read once per nt, used for both subtiles ----
        floatx4 S[2][4];
        #pragma unroll
        for (int nt = 0; nt < 4; nt++) {
            const short* krow = &Ks[(nt * 16 + l15) * LSTR + quad * 8];
            bf16x8 ka0 = *(const bf16x8*)krow;
            bf16x8 ka1 = *(const bf16x8*)(krow + 32);
            #pragma unroll
            for (int qt = 0; qt < 2; qt++) {
                floatx4 acc; acc[0] = acc[1] = acc[2] = acc[3] = 0.f;
                acc = __builtin_amdgcn_mfma_f32_16x16x32_bf16(ka0, qa[qt][0], acc, 0, 0, 0);
                acc = __builtin_amdgcn_mfma_f32_16x16x32_bf16(ka1, qa[qt][1], acc, 0, 0, 0);
                S[qt][nt] = acc;
            }
        }

        // ---- static softmax: p = exp(S + msk); packed b64 P-writes ----
        #pragma unroll
        for (int qt = 0; qt < 2; qt++)
            #pragma unroll
            for (int nt = 0; nt < 4; nt++) {
                bf16x4 pw;
                #pragma unroll
                for (int r = 0; r < 4; r++) {
                    float p = __expf(S[qt][nt][r] + msk[nt * 16 + quad * 4 + r]);
                    l_r[qt] += p;
                    pw[r] = f2bf_rn(p);
                }
                *(bf16x4*)&Ps[wave * 2 + qt][l15 * LSTR + nt * 16 + quad * 4] = pw;
            }

        // ---- O^T += V^T P^T; V-frag read once per nt, used for both subtiles ----
        bf16x8 pb[2][2];
        #pragma unroll
        for (int qt = 0; qt < 2; qt++) {
            pb[qt][0] = *(const bf16x8*)&Ps[wave * 2 + qt][l15 * LSTR + quad * 8];
            pb[qt][1] = *(const bf16x8*)&Ps[wave * 2 + qt][l15 * LSTR + 32 + quad * 8];
        }
        #pragma unroll
        for (int nt = 0; nt < 4; nt++) {
            const short* vrow = &Vs[(nt * 16 + l15) * LSTR + quad * 8];
            bf16x8 va0 = *(const bf16x8*)vrow;
            bf16x8 va1 = *(const bf16x8*)(vrow + 32);
            #pragma unroll
            for (int qt = 0; qt < 2; qt++) {
                O[qt][nt] = __builtin_amdgcn_mfma_f32_16x16x32_bf16(va0, pb[qt][0], O[qt][nt], 0, 0, 0);
                O[qt][nt] = __builtin_amdgcn_mfma_f32_16x16x32_bf16(va1, pb[qt][1], O[qt][nt], 0, 0, 0);
            }
        }
    }

    // ---- row-sum + write ----
    #pragma unroll
    for (int qt = 0; qt < 2; qt++) {
        float l = l_r[qt];
        l += __shfl_xor(l, 16);
        l += __shfl_xor(l, 32);
        const float inv = 1.0f / l;
        int row = q0 + qt * 64 + wave * 16 + l15;
        short* cp = (short*)ctx + ((size_t)(b * Ll + row)) * Cc + h * Dd;
        #pragma unroll
        for (int nt = 0; nt < 4; nt++) {
            bf16x4 ov;
            #pragma unroll
            for (int r = 0; r < 4; r++) ov[r] = f2bf_rn(O[qt][nt][r] * inv);
            *(bf16x4*)&cp[nt * 16 + quad * 4] = ov;
        }
    }
}

extern "C" void kernel_launch(void* const* d_in, const int* in_sizes, int n_in,
                              void* d_out, int out_size, void* d_ws, size_t ws_size,
                              hipStream_t stream) {
    const float* x    = (const float*)d_in[0];
    const int*   mask = (const int*)d_in[1];
    const float* Wq   = (const float*)d_in[2];
    const float* Wk   = (const float*)d_in[3];
    const float* Wv   = (const float*)d_in[4];
    const float* Wo   = (const float*)d_in[5];
    const float* bo   = (const float*)d_in[6];
    float* out = (float*)d_out;

    const size_t per = (size_t)Bb * Hh * Ll * Dd;   // 4 Mi elements
    bf16* qbuf = (bf16*)d_ws;
    bf16* kbuf = qbuf + per;
    bf16* vbuf = kbuf + per;            // transposed [B,H,D,L]
    bf16* xb   = vbuf + per;            // also used as ctx after x is dead
    bf16* wqkv = xb + per;              // [3072, 1024]
    bf16* wob  = wqkv + (size_t)3 * Cc * Cc;
    bf16* ctx  = xb;

    const int M = Bb * Ll;   // 4096

    convert_bf16<<<(Bb*Ll*Cc/8 + 4*Cc*Cc/8) / 256, 256, 0, stream>>>(
        x, Wq, Wk, Wv, Wo, xb, wqkv, wob);

    // fused QKV projection + RoPE + Q-scale + V-transpose
    dim3 gQKV(3 * Cc / 128, M / 128);
    gemm_mfma<0><<<gQKV, 256, 0, stream>>>(xb, wqkv, qbuf, kbuf, vbuf,
                                           nullptr, nullptr, M, 3 * Cc, Cc);

    attn_mfma<<<Bb * Hh * (Ll / 128), 256, 0, stream>>>(qbuf, kbuf, vbuf, mask, ctx);

    // output projection: [4096, 1024] fp32 + bias
    dim3 gOut(Cc / 128, M / 128);
    gemm_mfma<1><<<gOut, 256, 0, stream>>>(ctx, wob, nullptr, nullptr, nullptr,
                                           out, bo, M, Cc, Cc);
}

// Round 9
// 211.987 us; speedup vs baseline: 24.6985x; 1.0076x over previous
//
#include <hip/hip_runtime.h>
#include <hip/hip_bf16.h>

typedef __hip_bfloat16 bf16;
typedef short bf16x8 __attribute__((ext_vector_type(8)));
typedef short bf16x4 __attribute__((ext_vector_type(4)));
typedef float floatx4 __attribute__((ext_vector_type(4)));

#define Bb 2
#define Ll 2048
#define Cc 1024
#define Hh 16
#define Dd 64
// ln(50000)/32
#define INVFREQ_LN 0.3381180763f
// plain 1/sqrt(D) folded into Q; softmax uses __expf (natural)
#define QSCALE 0.125f

#define GLD16(gp, lp) __builtin_amdgcn_global_load_lds( \
    (const __attribute__((address_space(1))) void*)(gp), \
    (__attribute__((address_space(3))) void*)(lp), 16, 0, 0)

__device__ inline short f2bf(float f) {
    __hip_bfloat16 h = __float2bfloat16(f);
    return *reinterpret_cast<short*>(&h);
}
// fast round-to-nearest bf16 (ties-away); fine for finite positive values
__device__ inline short f2bf_rn(float f) {
    return (short)((__float_as_uint(f) + 0x8000u) >> 16);
}

// ---------------- convert fp32 inputs to bf16 workspace ----------------
__global__ __launch_bounds__(256) void convert_bf16(
    const float* __restrict__ x, const float* __restrict__ wq,
    const float* __restrict__ wk, const float* __restrict__ wv,
    const float* __restrict__ wo,
    bf16* __restrict__ xb, bf16* __restrict__ wqkv, bf16* __restrict__ wob)
{
    const int XN = (Bb * Ll * Cc) / 8;   // 524288
    const int WN = (Cc * Cc) / 8;        // 131072
    int i = blockIdx.x * 256 + threadIdx.x;
    const float* src; bf16* dst;
    if (i < XN)               { src = x  + (size_t)i * 8;                 dst = xb   + (size_t)i * 8; }
    else if (i < XN + WN)     { int j = i - XN;        src = wq + (size_t)j * 8; dst = wqkv + (size_t)j * 8; }
    else if (i < XN + 2*WN)   { int j = i - XN - WN;   src = wk + (size_t)j * 8; dst = wqkv + (size_t)Cc*Cc     + (size_t)j * 8; }
    else if (i < XN + 3*WN)   { int j = i - XN - 2*WN; src = wv + (size_t)j * 8; dst = wqkv + (size_t)Cc*Cc*2   + (size_t)j * 8; }
    else                      { int j = i - XN - 3*WN; src = wo + (size_t)j * 8; dst = wob  + (size_t)j * 8; }
    float4 a = *reinterpret_cast<const float4*>(src);
    float4 b = *reinterpret_cast<const float4*>(src + 4);
    float vv[8] = {a.x, a.y, a.z, a.w, b.x, b.y, b.z, b.w};
    bf16x8 o;
    #pragma unroll
    for (int t = 0; t < 8; t++) o[t] = f2bf(vv[t]);
    *reinterpret_cast<bf16x8*>(dst) = o;
}

// ---------------- MFMA GEMM: C = A[M,K] . W[N,K]^T, all bf16 ----------------
// MODE 0: N=3072 fused QKV. Epilogue: RoPE+scale on q/k -> [B,H,L,D];
//         V written TRANSPOSED -> [B,H,D,L].
// MODE 1: N=1024, out fp32 [M,N] + bias
template <int MODE>
__global__ __launch_bounds__(256) void gemm_mfma(
    const bf16* __restrict__ A, const bf16* __restrict__ W,
    bf16* __restrict__ qb, bf16* __restrict__ kb, bf16* __restrict__ vb,
    float* __restrict__ outf, const float* __restrict__ bias,
    int M, int N, int K)
{
    __shared__ __align__(16) short As[128 * 32];
    __shared__ __align__(16) short Bs[128 * 32];

    const int tid  = threadIdx.x;
    const int wave = tid >> 6;
    const int lane = tid & 63;
    const int l15  = lane & 15;
    const int quad = lane >> 4;
    const int wm   = wave >> 1;       // 2x2 wave grid
    const int wn   = wave & 1;
    const int m0   = blockIdx.y * 128;
    const int n0   = blockIdx.x * 128;

    const int ar = tid >> 2;          // 0..63 (row within 64-row chunk)
    const int ac = (tid & 3) * 8;     // 0,8,16,24

    floatx4 acc[4][4];
    #pragma unroll
    for (int mt = 0; mt < 4; mt++)
        #pragma unroll
        for (int nt = 0; nt < 4; nt++)
            #pragma unroll
            for (int r = 0; r < 4; r++) acc[mt][nt][r] = 0.f;

    for (int k0 = 0; k0 < K; k0 += 32) {
        __syncthreads();
        #pragma unroll
        for (int p = 0; p < 2; p++) {
            const bf16* gp = A + (size_t)(m0 + p * 64 + ar) * K + k0 + ac;
            GLD16(gp, &As[(p * 64 + ar) * 32 + ac]);
        }
        #pragma unroll
        for (int p = 0; p < 2; p++) {
            const bf16* gp = W + (size_t)(n0 + p * 64 + ar) * K + k0 + ac;
            GLD16(gp, &Bs[(p * 64 + ar) * 32 + ac]);
        }
        __syncthreads();

        bf16x8 af[4], bfr[4];
        #pragma unroll
        for (int mt = 0; mt < 4; mt++)
            af[mt] = *(const bf16x8*)&As[(wm * 64 + mt * 16 + l15) * 32 + quad * 8];
        #pragma unroll
        for (int nt = 0; nt < 4; nt++)
            bfr[nt] = *(const bf16x8*)&Bs[(wn * 64 + nt * 16 + l15) * 32 + quad * 8];
        #pragma unroll
        for (int mt = 0; mt < 4; mt++)
            #pragma unroll
            for (int nt = 0; nt < 4; nt++)
                acc[mt][nt] = __builtin_amdgcn_mfma_f32_16x16x32_bf16(
                    af[mt], bfr[nt], acc[mt][nt], 0, 0, 0);
    }

    // epilogue: C[row][col], row = m0+wm*64+mt*16+quad*4+r, col = n0+wn*64+nt*16+l15
    if (MODE == 1) {
        #pragma unroll
        for (int mt = 0; mt < 4; mt++)
            #pragma unroll
            for (int r = 0; r < 4; r++) {
                int row = m0 + wm * 64 + mt * 16 + quad * 4 + r;
                #pragma unroll
                for (int nt = 0; nt < 4; nt++) {
                    int col = n0 + wn * 64 + nt * 16 + l15;
                    outf[(size_t)row * N + col] = acc[mt][nt][r] + bias[col];
                }
            }
    } else {
        const int colbase = n0 + wn * 64;          // 64-aligned -> one (which,h)
        const int which   = colbase >> 10;         // 0=q, 1=k, 2=v
        const int hh      = (colbase & (Cc - 1)) >> 6;
        if (which == 2) {
            // V transposed: vb[((b*H+h)*D + d) * L + l]
            #pragma unroll
            for (int mt = 0; mt < 4; mt++)
                #pragma unroll
                for (int r = 0; r < 4; r++) {
                    int row = m0 + wm * 64 + mt * 16 + quad * 4 + r;
                    int b = row >> 11, l = row & (Ll - 1);
                    size_t base = (size_t)(b * Hh + hh) * Dd * Ll + l;
                    #pragma unroll
                    for (int nt = 0; nt < 4; nt++) {
                        int d = nt * 16 + l15;
                        vb[base + (size_t)d * Ll] = __float2bfloat16(acc[mt][nt][r]);
                    }
                }
        } else {
            bf16* dst = which ? kb : qb;
            const float qs = which ? 1.0f : QSCALE;
            const float base0 = __expf(-(float)l15 * INVFREQ_LN);
            const float base1 = __expf(-(float)(l15 + 16) * INVFREQ_LN);
            #pragma unroll
            for (int mt = 0; mt < 4; mt++)
                #pragma unroll
                for (int r = 0; r < 4; r++) {
                    int row = m0 + wm * 64 + mt * 16 + quad * 4 + r;
                    int b = row >> 11, l = row & (Ll - 1);
                    size_t rb = ((size_t)(b * Hh + hh) * Ll + l) * Dd;
                    #pragma unroll
                    for (int nt2 = 0; nt2 < 2; nt2++) {
                        float fr = (float)l * (nt2 ? base1 : base0);
                        float sn, cs;
                        __sincosf(fr, &sn, &cs);
                        float x1 = acc[mt][nt2][r];
                        float x2 = acc[mt][nt2 + 2][r];
                        dst[rb + nt2 * 16 + l15]      = __float2bfloat16((x1 * cs - x2 * sn) * qs);
                        dst[rb + nt2 * 16 + l15 + 32] = __float2bfloat16((x2 * cs + x1 * sn) * qs);
                    }
                }
        }
    }
}

// ---------------- Flash attention with MFMA (S^T form, static softmax) ----------------
// q pre-scaled by 0.125 and roped; k roped; v transposed [B,H,D,L].
// Block = 512 threads = 8 waves; each wave owns one 16-q subtile (128 q/block).
// S^T = K.Q^T  -> lane holds S[q=l15][key=nt*16+quad*4+r]
// P stored [q][key] row-major; re-read as B-fragment (b128).
// O^T = V^T.P^T -> lane holds O[q=l15][d=nt*16+quad*4+r]
#define LSTR 72

__global__ __launch_bounds__(512) void attn_mfma(
    const bf16* __restrict__ q, const bf16* __restrict__ k, const bf16* __restrict__ vt,
    const int* __restrict__ mask, bf16* __restrict__ ctx)
{
    __shared__ __align__(16) short Ks[64 * LSTR];
    __shared__ __align__(16) short Vs[64 * LSTR];
    __shared__ __align__(16) short Ps[8][16 * LSTR];
    __shared__ __align__(16) float msk[64];

    const int tid  = threadIdx.x;
    const int wave = tid >> 6;
    const int lane = tid & 63;
    const int l15  = lane & 15;
    const int quad = lane >> 4;

    const int bh = blockIdx.x & 31;           // (b*H + h) -> fixed XCD per head
    const int q0 = (blockIdx.x >> 5) << 7;    // 128-query tile start
    const int b  = bh >> 4;
    const int h  = bh & (Hh - 1);

    const short* qb  = (const short*)(q  + (size_t)bh * Ll * Dd);
    const short* kb  = (const short*)(k  + (size_t)bh * Ll * Dd);
    const short* vtb = (const short*)(vt + (size_t)bh * Dd * Ll);
    const int* mrow = mask + b * Ll;

    // Q fragment: wave's 16 rows
    const int qrow = q0 + wave * 16 + l15;
    bf16x8 qa0 = *(const bf16x8*)(qb + (size_t)qrow * Dd + quad * 8);
    bf16x8 qa1 = *(const bf16x8*)(qb + (size_t)qrow * Dd + 32 + quad * 8);

    floatx4 O[4];
    float l_r = 0.f;
    #pragma unroll
    for (int nt = 0; nt < 4; nt++)
        #pragma unroll
        for (int r = 0; r < 4; r++) O[nt][r] = 0.f;

    for (int s0 = 0; s0 < Ll; s0 += 64) {
        __syncthreads();
        // ---- stage K tile [64 s][64 d]: 512 threads cover it in one pass ----
        {
            const int n  = tid >> 3;           // 0..63
            const int c8 = (tid & 7) << 3;     // 0..56
            *(bf16x8*)&Ks[n * LSTR + c8] =
                *(const bf16x8*)(kb + (size_t)(s0 + n) * Dd + c8);
        }
        // ---- stage V tile [64 d][64 s] from transposed global: one pass ----
        {
            const int d = tid >> 3;
            const int o = (tid & 7) << 3;
            *(bf16x8*)&Vs[d * LSTR + o] =
                *(const bf16x8*)(vtb + (size_t)d * Ll + s0 + o);
        }
        if (tid < 64) msk[tid] = mrow[s0 + tid] ? 0.0f : -1e30f;
        __syncthreads();

        // ---- S^T = K Q^T: lane holds S[q=l15][key=nt*16+quad*4+r] ----
        floatx4 S[4];
        #pragma unroll
        for (int nt = 0; nt < 4; nt++) {
            const short* krow = &Ks[(nt * 16 + l15) * LSTR + quad * 8];
            bf16x8 ka0 = *(const bf16x8*)krow;
            bf16x8 ka1 = *(const bf16x8*)(krow + 32);
            floatx4 acc; acc[0] = acc[1] = acc[2] = acc[3] = 0.f;
            acc = __builtin_amdgcn_mfma_f32_16x16x32_bf16(ka0, qa0, acc, 0, 0, 0);
            acc = __builtin_amdgcn_mfma_f32_16x16x32_bf16(ka1, qa1, acc, 0, 0, 0);
            S[nt] = acc;
        }

        // ---- static softmax: p = exp(S + msk); packed b64 P-writes ----
        #pragma unroll
        for (int nt = 0; nt < 4; nt++) {
            float4 m4 = *(const float4*)&msk[nt * 16 + quad * 4];
            float mv[4] = {m4.x, m4.y, m4.z, m4.w};
            bf16x4 pw;
            #pragma unroll
            for (int r = 0; r < 4; r++) {
                float p = __expf(S[nt][r] + mv[r]);
                l_r += p;
                pw[r] = f2bf_rn(p);
            }
            *(bf16x4*)&Ps[wave][l15 * LSTR + nt * 16 + quad * 4] = pw;
        }

        // ---- O^T += V^T P^T: A=Vs rows (d), B=Ps rows (q) ----
        bf16x8 pb0 = *(const bf16x8*)&Ps[wave][l15 * LSTR + quad * 8];
        bf16x8 pb1 = *(const bf16x8*)&Ps[wave][l15 * LSTR + 32 + quad * 8];
        #pragma unroll
        for (int nt = 0; nt < 4; nt++) {
            const short* vrow = &Vs[(nt * 16 + l15) * LSTR + quad * 8];
            bf16x8 va0 = *(const bf16x8*)vrow;
            bf16x8 va1 = *(const bf16x8*)(vrow + 32);
            O[nt] = __builtin_amdgcn_mfma_f32_16x16x32_bf16(va0, pb0, O[nt], 0, 0, 0);
            O[nt] = __builtin_amdgcn_mfma_f32_16x16x32_bf16(va1, pb1, O[nt], 0, 0, 0);
        }
    }

    // ---- row-sum: lanes with same l15 across quads hold the same q ----
    float l = l_r;
    l += __shfl_xor(l, 16);
    l += __shfl_xor(l, 32);
    const float inv = 1.0f / l;

    // ---- write ctx: lane holds O[q=l15][d=nt*16+quad*4+r] -> b64 stores ----
    {
        int row = q0 + wave * 16 + l15;
        short* cp = (short*)ctx + ((size_t)(b * Ll + row)) * Cc + h * Dd;
        #pragma unroll
        for (int nt = 0; nt < 4; nt++) {
            bf16x4 ov;
            #pragma unroll
            for (int r = 0; r < 4; r++) ov[r] = f2bf_rn(O[nt][r] * inv);
            *(bf16x4*)&cp[nt * 16 + quad * 4] = ov;
        }
    }
}

extern "C" void kernel_launch(void* const* d_in, const int* in_sizes, int n_in,
                              void* d_out, int out_size, void* d_ws, size_t ws_size,
                              hipStream_t stream) {
    const float* x    = (const float*)d_in[0];
    const int*   mask = (const int*)d_in[1];
    const float* Wq   = (const float*)d_in[2];
    const float* Wk   = (const float*)d_in[3];
    const float* Wv   = (const float*)d_in[4];
    const float* Wo   = (const float*)d_in[5];
    const float* bo   = (const float*)d_in[6];
    float* out = (float*)d_out;

    const size_t per = (size_t)Bb * Hh * Ll * Dd;   // 4 Mi elements
    bf16* qbuf = (bf16*)d_ws;
    bf16* kbuf = qbuf + per;
    bf16* vbuf = kbuf + per;            // transposed [B,H,D,L]
    bf16* xb   = vbuf + per;            // also used as ctx after x is dead
    bf16* wqkv = xb + per;              // [3072, 1024]
    bf16* wob  = wqkv + (size_t)3 * Cc * Cc;
    bf16* ctx  = xb;

    const int M = Bb * Ll;   // 4096

    convert_bf16<<<(Bb*Ll*Cc/8 + 4*Cc*Cc/8) / 256, 256, 0, stream>>>(
        x, Wq, Wk, Wv, Wo, xb, wqkv, wob);

    // fused QKV projection + RoPE + Q-scale + V-transpose
    dim3 gQKV(3 * Cc / 128, M / 128);
    gemm_mfma<0><<<gQKV, 256, 0, stream>>>(xb, wqkv, qbuf, kbuf, vbuf,
                                           nullptr, nullptr, M, 3 * Cc, Cc);

    attn_mfma<<<Bb * Hh * (Ll / 128), 512, 0, stream>>>(qbuf, kbuf, vbuf, mask, ctx);

    // output projection: [4096, 1024] fp32 + bias
    dim3 gOut(Cc / 128, M / 128);
    gemm_mfma<1><<<gOut, 256, 0, stream>>>(ctx, wob, nullptr, nullptr, nullptr,
                                           out, bo, M, Cc, Cc);
}

// Round 10
// 202.873 us; speedup vs baseline: 25.8081x; 1.0449x over previous
//
#include <hip/hip_runtime.h>
#include <hip/hip_bf16.h>

typedef __hip_bfloat16 bf16;
typedef short bf16x8 __attribute__((ext_vector_type(8)));
typedef short bf16x4 __attribute__((ext_vector_type(4)));
typedef float floatx4 __attribute__((ext_vector_type(4)));

#define Bb 2
#define Ll 2048
#define Cc 1024
#define Hh 16
#define Dd 64
// ln(50000)/32
#define INVFREQ_LN 0.3381180763f
// plain 1/sqrt(D) folded into Q; softmax uses __expf (natural)
#define QSCALE 0.125f

#define GLD16(gp, lp) __builtin_amdgcn_global_load_lds( \
    (const __attribute__((address_space(1))) void*)(gp), \
    (__attribute__((address_space(3))) void*)(lp), 16, 0, 0)

__device__ inline short f2bf(float f) {
    __hip_bfloat16 h = __float2bfloat16(f);
    return *reinterpret_cast<short*>(&h);
}
// fast round-to-nearest bf16; fine for finite values
__device__ inline short f2bf_rn(float f) {
    return (short)((__float_as_uint(f) + 0x8000u) >> 16);
}

// ---------------- convert fp32 inputs to bf16 workspace ----------------
__global__ __launch_bounds__(256) void convert_bf16(
    const float* __restrict__ x, const float* __restrict__ wq,
    const float* __restrict__ wk, const float* __restrict__ wv,
    const float* __restrict__ wo,
    bf16* __restrict__ xb, bf16* __restrict__ wqkv, bf16* __restrict__ wob)
{
    const int XN = (Bb * Ll * Cc) / 8;   // 524288
    const int WN = (Cc * Cc) / 8;        // 131072
    int i = blockIdx.x * 256 + threadIdx.x;
    const float* src; bf16* dst;
    if (i < XN)               { src = x  + (size_t)i * 8;                 dst = xb   + (size_t)i * 8; }
    else if (i < XN + WN)     { int j = i - XN;        src = wq + (size_t)j * 8; dst = wqkv + (size_t)j * 8; }
    else if (i < XN + 2*WN)   { int j = i - XN - WN;   src = wk + (size_t)j * 8; dst = wqkv + (size_t)Cc*Cc     + (size_t)j * 8; }
    else if (i < XN + 3*WN)   { int j = i - XN - 2*WN; src = wv + (size_t)j * 8; dst = wqkv + (size_t)Cc*Cc*2   + (size_t)j * 8; }
    else                      { int j = i - XN - 3*WN; src = wo + (size_t)j * 8; dst = wob  + (size_t)j * 8; }
    float4 a = *reinterpret_cast<const float4*>(src);
    float4 b = *reinterpret_cast<const float4*>(src + 4);
    float vv[8] = {a.x, a.y, a.z, a.w, b.x, b.y, b.z, b.w};
    bf16x8 o;
    #pragma unroll
    for (int t = 0; t < 8; t++) o[t] = f2bf(vv[t]);
    *reinterpret_cast<bf16x8*>(dst) = o;
}

// ---------------- MFMA GEMM: C = A[M,K] . W[N,K]^T, all bf16 ----------------
// MODE 0: N=3072 fused QKV. Epilogue: RoPE+scale on q (linear layout);
//         K written with XOR-swizzled 16B groups (group g of row s at g^(s&7));
//         V written TRANSPOSED [B,H,D,L] with per-64-chunk XOR swizzle by (d&7).
// MODE 1: N=1024, out fp32 [M,N] + bias
template <int MODE>
__global__ __launch_bounds__(256) void gemm_mfma(
    const bf16* __restrict__ A, const bf16* __restrict__ W,
    bf16* __restrict__ qb, bf16* __restrict__ kb, bf16* __restrict__ vb,
    float* __restrict__ outf, const float* __restrict__ bias,
    int M, int N, int K)
{
    __shared__ __align__(16) short As[128 * 32];
    __shared__ __align__(16) short Bs[128 * 32];

    const int tid  = threadIdx.x;
    const int wave = tid >> 6;
    const int lane = tid & 63;
    const int l15  = lane & 15;
    const int quad = lane >> 4;
    const int wm   = wave >> 1;       // 2x2 wave grid
    const int wn   = wave & 1;
    const int m0   = blockIdx.y * 128;
    const int n0   = blockIdx.x * 128;

    const int ar = tid >> 2;          // 0..63 (row within 64-row chunk)
    const int ac = (tid & 3) * 8;     // 0,8,16,24

    floatx4 acc[4][4];
    #pragma unroll
    for (int mt = 0; mt < 4; mt++)
        #pragma unroll
        for (int nt = 0; nt < 4; nt++)
            #pragma unroll
            for (int r = 0; r < 4; r++) acc[mt][nt][r] = 0.f;

    for (int k0 = 0; k0 < K; k0 += 32) {
        __syncthreads();
        #pragma unroll
        for (int p = 0; p < 2; p++) {
            const bf16* gp = A + (size_t)(m0 + p * 64 + ar) * K + k0 + ac;
            GLD16(gp, &As[(p * 64 + ar) * 32 + ac]);
        }
        #pragma unroll
        for (int p = 0; p < 2; p++) {
            const bf16* gp = W + (size_t)(n0 + p * 64 + ar) * K + k0 + ac;
            GLD16(gp, &Bs[(p * 64 + ar) * 32 + ac]);
        }
        __syncthreads();

        bf16x8 af[4], bfr[4];
        #pragma unroll
        for (int mt = 0; mt < 4; mt++)
            af[mt] = *(const bf16x8*)&As[(wm * 64 + mt * 16 + l15) * 32 + quad * 8];
        #pragma unroll
        for (int nt = 0; nt < 4; nt++)
            bfr[nt] = *(const bf16x8*)&Bs[(wn * 64 + nt * 16 + l15) * 32 + quad * 8];
        #pragma unroll
        for (int mt = 0; mt < 4; mt++)
            #pragma unroll
            for (int nt = 0; nt < 4; nt++)
                acc[mt][nt] = __builtin_amdgcn_mfma_f32_16x16x32_bf16(
                    af[mt], bfr[nt], acc[mt][nt], 0, 0, 0);
    }

    // epilogue: C[row][col], row = m0+wm*64+mt*16+quad*4+r, col = n0+wn*64+nt*16+l15
    if (MODE == 1) {
        #pragma unroll
        for (int mt = 0; mt < 4; mt++)
            #pragma unroll
            for (int r = 0; r < 4; r++) {
                int row = m0 + wm * 64 + mt * 16 + quad * 4 + r;
                #pragma unroll
                for (int nt = 0; nt < 4; nt++) {
                    int col = n0 + wn * 64 + nt * 16 + l15;
                    outf[(size_t)row * N + col] = acc[mt][nt][r] + bias[col];
                }
            }
    } else {
        const int colbase = n0 + wn * 64;          // 64-aligned -> one (which,h)
        const int which   = colbase >> 10;         // 0=q, 1=k, 2=v
        const int hh      = (colbase & (Cc - 1)) >> 6;
        if (which == 2) {
            // V transposed + swizzled: element (d,l) at
            // head + d*L + (l&~63) + ((((l>>3)&7) ^ (d&7))<<3) + (l&7)
            #pragma unroll
            for (int mt = 0; mt < 4; mt++)
                #pragma unroll
                for (int r = 0; r < 4; r++) {
                    int row = m0 + wm * 64 + mt * 16 + quad * 4 + r;
                    int b = row >> 11, l = row & (Ll - 1);
                    size_t head = (size_t)(b * Hh + hh) * Dd * Ll;
                    int lbase = (l & ~63) | (l & 7);
                    int lg    = (l >> 3) & 7;
                    #pragma unroll
                    for (int nt = 0; nt < 4; nt++) {
                        int d = nt * 16 + l15;
                        int pos = lbase | ((lg ^ (d & 7)) << 3);
                        vb[head + (size_t)d * Ll + pos] = __float2bfloat16(acc[mt][nt][r]);
                    }
                }
        } else {
            bf16* dst = which ? kb : qb;
            const float qs = which ? 1.0f : QSCALE;
            const float base0 = __expf(-(float)l15 * INVFREQ_LN);
            const float base1 = __expf(-(float)(l15 + 16) * INVFREQ_LN);
            #pragma unroll
            for (int mt = 0; mt < 4; mt++)
                #pragma unroll
                for (int r = 0; r < 4; r++) {
                    int row = m0 + wm * 64 + mt * 16 + quad * 4 + r;
                    int b = row >> 11, l = row & (Ll - 1);
                    size_t rb = ((size_t)(b * Hh + hh) * Ll + l) * Dd;
                    #pragma unroll
                    for (int nt2 = 0; nt2 < 2; nt2++) {
                        float fr = (float)l * (nt2 ? base1 : base0);
                        float sn, cs;
                        __sincosf(fr, &sn, &cs);
                        float x1 = acc[mt][nt2][r];
                        float x2 = acc[mt][nt2 + 2][r];
                        float o1 = (x1 * cs - x2 * sn) * qs;
                        float o2 = (x2 * cs + x1 * sn) * qs;
                        int d1 = nt2 * 16 + l15;
                        int d2 = d1 + 32;
                        if (which == 1) {
                            // K swizzle: group g of row l stored at g^(l&7)
                            int sw = l & 7;
                            int a1 = ((((d1 >> 3) ^ sw)) << 3) | (d1 & 7);
                            int a2 = ((((d2 >> 3) ^ sw)) << 3) | (d2 & 7);
                            dst[rb + a1] = __float2bfloat16(o1);
                            dst[rb + a2] = __float2bfloat16(o2);
                        } else {
                            dst[rb + d1] = __float2bfloat16(o1);
                            dst[rb + d2] = __float2bfloat16(o2);
                        }
                    }
                }
        }
    }
}

// ---------------- Flash attention: GLD16 double-buffered K/V, 1 barrier/tile ----------------
// q pre-scaled+roped (linear); k roped+swizzled; v transposed [B,H,D,L]+swizzled.
// Block = 512 threads = 8 waves; each wave one 16-q subtile (128 q/block).
// S^T = K.Q^T -> lane holds S[q=l15][key=nt*16+quad*4+r]
// P through LDS (padded); O^T = V^T.P^T -> lane holds O[q=l15][d=nt*16+quad*4+r]
#define LSTR 72

__global__ __launch_bounds__(512) void attn_mfma(
    const bf16* __restrict__ q, const bf16* __restrict__ k, const bf16* __restrict__ vt,
    const int* __restrict__ mask, bf16* __restrict__ ctx)
{
    __shared__ __align__(16) short Ks[2][64 * 64];
    __shared__ __align__(16) short Vs[2][64 * 64];
    __shared__ __align__(16) short Ps[8][16 * LSTR];
    __shared__ __align__(16) float msk[2][64];

    const int tid  = threadIdx.x;
    const int wave = tid >> 6;
    const int lane = tid & 63;
    const int l15  = lane & 15;
    const int quad = lane >> 4;

    const int bh = blockIdx.x & 31;           // (b*H + h) -> fixed XCD per head
    const int q0 = (blockIdx.x >> 5) << 7;    // 128-query tile start
    const int b  = bh >> 4;
    const int h  = bh & (Hh - 1);

    const short* qb  = (const short*)(q  + (size_t)bh * Ll * Dd);
    const short* kb  = (const short*)(k  + (size_t)bh * Ll * Dd);
    const short* vtb = (const short*)(vt + (size_t)bh * Dd * Ll);
    const int* mrow = mask + b * Ll;

    // Q fragment: wave's 16 rows (linear layout)
    const int qrow = q0 + wave * 16 + l15;
    bf16x8 qa0 = *(const bf16x8*)(qb + (size_t)qrow * Dd + quad * 8);
    bf16x8 qa1 = *(const bf16x8*)(qb + (size_t)qrow * Dd + 32 + quad * 8);

    // swizzled group offsets (shorts) within a 64-short row, row&7 == l15&7
    const int g0 = ((quad ^ (l15 & 7)) << 3);
    const int g1 = (((quad + 4) ^ (l15 & 7)) << 3);

    // staging pointers: thread covers row tid>>3, group tid&7 of a 64x64 tile
    const short* vgp = vtb + (size_t)(tid >> 3) * Ll + ((tid & 7) << 3);
    short* ksl = &Ks[0][0] + tid * 8;   // lane-linear LDS dest (x8 shorts = 16B)
    short* vsl = &Vs[0][0] + tid * 8;
    const int lbuf = 64 * 64;           // buffer stride in shorts

    floatx4 O[4];
    float l_r = 0.f;
    #pragma unroll
    for (int nt = 0; nt < 4; nt++)
        #pragma unroll
        for (int r = 0; r < 4; r++) O[nt][r] = 0.f;

    // prologue: stage tile 0 into buffer 0
    GLD16(kb + tid * 8, ksl);
    GLD16(vgp, vsl);
    if (tid < 64) msk[0][tid] = mrow[tid] ? 0.0f : -1e30f;

    for (int t = 0; t < Ll / 64; t++) {
        const int cur = t & 1;
        __syncthreads();   // drains this tile's GLDs (vmcnt) + msk writes (lgkm)
        if (t < Ll / 64 - 1) {
            const int s1 = (t + 1) << 6;
            GLD16(kb + (size_t)s1 * Dd + tid * 8, ksl + (cur ^ 1) * lbuf);
            GLD16(vgp + s1,                       vsl + (cur ^ 1) * lbuf);
            if (tid < 64) msk[cur ^ 1][tid] = mrow[s1 + tid] ? 0.0f : -1e30f;
        }

        // ---- S^T = K Q^T: lane holds S[q=l15][key=nt*16+quad*4+r] ----
        const short* Kc = &Ks[cur][0];
        const short* Vc = &Vs[cur][0];
        floatx4 S[4];
        #pragma unroll
        for (int nt = 0; nt < 4; nt++) {
            const short* krow = Kc + (nt * 16 + l15) * 64;
            bf16x8 ka0 = *(const bf16x8*)(krow + g0);
            bf16x8 ka1 = *(const bf16x8*)(krow + g1);
            floatx4 acc; acc[0] = acc[1] = acc[2] = acc[3] = 0.f;
            acc = __builtin_amdgcn_mfma_f32_16x16x32_bf16(ka0, qa0, acc, 0, 0, 0);
            acc = __builtin_amdgcn_mfma_f32_16x16x32_bf16(ka1, qa1, acc, 0, 0, 0);
            S[nt] = acc;
        }

        // ---- static softmax: p = exp(S + msk); packed b64 P-writes ----
        #pragma unroll
        for (int nt = 0; nt < 4; nt++) {
            float4 m4 = *(const float4*)&msk[cur][nt * 16 + quad * 4];
            float mv[4] = {m4.x, m4.y, m4.z, m4.w};
            bf16x4 pw;
            #pragma unroll
            for (int r = 0; r < 4; r++) {
                float p = __expf(S[nt][r] + mv[r]);
                l_r += p;
                pw[r] = f2bf_rn(p);
            }
            *(bf16x4*)&Ps[wave][l15 * LSTR + nt * 16 + quad * 4] = pw;
        }

        // ---- O^T += V^T P^T: A=Vs rows (d, swizzled), B=Ps rows (q) ----
        bf16x8 pb0 = *(const bf16x8*)&Ps[wave][l15 * LSTR + quad * 8];
        bf16x8 pb1 = *(const bf16x8*)&Ps[wave][l15 * LSTR + 32 + quad * 8];
        #pragma unroll
        for (int nt = 0; nt < 4; nt++) {
            const short* vrow = Vc + (nt * 16 + l15) * 64;
            bf16x8 va0 = *(const bf16x8*)(vrow + g0);
            bf16x8 va1 = *(const bf16x8*)(vrow + g1);
            O[nt] = __builtin_amdgcn_mfma_f32_16x16x32_bf16(va0, pb0, O[nt], 0, 0, 0);
            O[nt] = __builtin_amdgcn_mfma_f32_16x16x32_bf16(va1, pb1, O[nt], 0, 0, 0);
        }
    }

    // ---- row-sum: lanes with same l15 across quads hold the same q ----
    float l = l_r;
    l += __shfl_xor(l, 16);
    l += __shfl_xor(l, 32);
    const float inv = 1.0f / l;

    // ---- write ctx: lane holds O[q=l15][d=nt*16+quad*4+r] -> b64 stores ----
    {
        int row = q0 + wave * 16 + l15;
        short* cp = (short*)ctx + ((size_t)(b * Ll + row)) * Cc + h * Dd;
        #pragma unroll
        for (int nt = 0; nt < 4; nt++) {
            bf16x4 ov;
            #pragma unroll
            for (int r = 0; r < 4; r++) ov[r] = f2bf_rn(O[nt][r] * inv);
            *(bf16x4*)&cp[nt * 16 + quad * 4] = ov;
        }
    }
}

extern "C" void kernel_launch(void* const* d_in, const int* in_sizes, int n_in,
                              void* d_out, int out_size, void* d_ws, size_t ws_size,
                              hipStream_t stream) {
    const float* x    = (const float*)d_in[0];
    const int*   mask = (const int*)d_in[1];
    const float* Wq   = (const float*)d_in[2];
    const float* Wk   = (const float*)d_in[3];
    const float* Wv   = (const float*)d_in[4];
    const float* Wo   = (const float*)d_in[5];
    const float* bo   = (const float*)d_in[6];
    float* out = (float*)d_out;

    const size_t per = (size_t)Bb * Hh * Ll * Dd;   // 4 Mi elements
    bf16* qbuf = (bf16*)d_ws;
    bf16* kbuf = qbuf + per;            // swizzled
    bf16* vbuf = kbuf + per;            // transposed [B,H,D,L], swizzled
    bf16* xb   = vbuf + per;            // also used as ctx after x is dead
    bf16* wqkv = xb + per;              // [3072, 1024]
    bf16* wob  = wqkv + (size_t)3 * Cc * Cc;
    bf16* ctx  = xb;

    const int M = Bb * Ll;   // 4096

    convert_bf16<<<(Bb*Ll*Cc/8 + 4*Cc*Cc/8) / 256, 256, 0, stream>>>(
        x, Wq, Wk, Wv, Wo, xb, wqkv, wob);

    // fused QKV projection + RoPE + Q-scale + K/V swizzle + V-transpose
    dim3 gQKV(3 * Cc / 128, M / 128);
    gemm_mfma<0><<<gQKV, 256, 0, stream>>>(xb, wqkv, qbuf, kbuf, vbuf,
                                           nullptr, nullptr, M, 3 * Cc, Cc);

    attn_mfma<<<Bb * Hh * (Ll / 128), 512, 0, stream>>>(qbuf, kbuf, vbuf, mask, ctx);

    // output projection: [4096, 1024] fp32 + bias
    dim3 gOut(Cc / 128, M / 128);
    gemm_mfma<1><<<gOut, 256, 0, stream>>>(ctx, wob, nullptr, nullptr, nullptr,
                                           out, bo, M, Cc, Cc);
}

// Round 11
// 191.440 us; speedup vs baseline: 27.3494x; 1.0597x over previous
//
#include <hip/hip_runtime.h>
#include <hip/hip_bf16.h>

typedef __hip_bfloat16 bf16;
typedef short bf16x8 __attribute__((ext_vector_type(8)));
typedef short bf16x4 __attribute__((ext_vector_type(4)));
typedef float floatx4 __attribute__((ext_vector_type(4)));

#define Bb 2
#define Ll 2048
#define Cc 1024
#define Hh 16
#define Dd 64
// ln(50000)/32
#define INVFREQ_LN 0.3381180763f
// plain 1/sqrt(D) folded into Q; softmax uses __expf (natural)
#define QSCALE 0.125f

#define GLD16(gp, lp) __builtin_amdgcn_global_load_lds( \
    (const __attribute__((address_space(1))) void*)(gp), \
    (__attribute__((address_space(3))) void*)(lp), 16, 0, 0)

__device__ inline short f2bf(float f) {
    __hip_bfloat16 h = __float2bfloat16(f);
    return *reinterpret_cast<short*>(&h);
}
// fast round-to-nearest bf16; fine for finite values
__device__ inline short f2bf_rn(float f) {
    return (short)((__float_as_uint(f) + 0x8000u) >> 16);
}

// ---------------- convert fp32 inputs to bf16 workspace ----------------
__global__ __launch_bounds__(256) void convert_bf16(
    const float* __restrict__ x, const float* __restrict__ wq,
    const float* __restrict__ wk, const float* __restrict__ wv,
    const float* __restrict__ wo,
    bf16* __restrict__ xb, bf16* __restrict__ wqkv, bf16* __restrict__ wob)
{
    const int XN = (Bb * Ll * Cc) / 8;   // 524288
    const int WN = (Cc * Cc) / 8;        // 131072
    int i = blockIdx.x * 256 + threadIdx.x;
    const float* src; bf16* dst;
    if (i < XN)               { src = x  + (size_t)i * 8;                 dst = xb   + (size_t)i * 8; }
    else if (i < XN + WN)     { int j = i - XN;        src = wq + (size_t)j * 8; dst = wqkv + (size_t)j * 8; }
    else if (i < XN + 2*WN)   { int j = i - XN - WN;   src = wk + (size_t)j * 8; dst = wqkv + (size_t)Cc*Cc     + (size_t)j * 8; }
    else if (i < XN + 3*WN)   { int j = i - XN - 2*WN; src = wv + (size_t)j * 8; dst = wqkv + (size_t)Cc*Cc*2   + (size_t)j * 8; }
    else                      { int j = i - XN - 3*WN; src = wo + (size_t)j * 8; dst = wob  + (size_t)j * 8; }
    float4 a = *reinterpret_cast<const float4*>(src);
    float4 b = *reinterpret_cast<const float4*>(src + 4);
    float vv[8] = {a.x, a.y, a.z, a.w, b.x, b.y, b.z, b.w};
    bf16x8 o;
    #pragma unroll
    for (int t = 0; t < 8; t++) o[t] = f2bf(vv[t]);
    *reinterpret_cast<bf16x8*>(dst) = o;
}

// ---------------- per-batch mask prefix scan ----------------
// cidx[b*L+l] = exclusive count of valid keys before l; valid[b] = total
__global__ __launch_bounds__(256) void mask_scan(
    const int* __restrict__ mask, int* __restrict__ cidx, int* __restrict__ valid)
{
    const int b   = blockIdx.x;
    const int tid = threadIdx.x;
    const int base = b * Ll + tid * 8;
    int m[8]; int s = 0;
    #pragma unroll
    for (int i = 0; i < 8; i++) { m[i] = mask[base + i] ? 1 : 0; s += m[i]; }
    const int lane = tid & 63;
    int x = s;
    #pragma unroll
    for (int off = 1; off < 64; off <<= 1) {
        int y = __shfl_up(x, off);
        if (lane >= off) x += y;
    }
    __shared__ int wtot[4];
    if (lane == 63) wtot[tid >> 6] = x;       // inclusive wave total
    __syncthreads();
    int wbase = 0;
    const int w = tid >> 6;
    #pragma unroll
    for (int i = 0; i < 4; i++) if (i < w) wbase += wtot[i];
    int run = wbase + (x - s);                // exclusive base for this thread
    #pragma unroll
    for (int i = 0; i < 8; i++) { cidx[base + i] = run; run += m[i]; }
    if (tid == 255) valid[b] = run;
}

// ---------------- MFMA GEMM: C = A[M,K] . W[N,K]^T, all bf16 ----------------
// MODE 0: N=3072 fused QKV. Epilogue: RoPE+scale on q (linear layout);
//         K/V written COMPACTED by cidx (masked keys dropped), K with XOR-swizzled
//         16B groups (group g of row c at g^(c&7)); V transposed [B,H,D,L'] with
//         per-64-chunk XOR swizzle by (d&7).
// MODE 1: N=1024, out fp32 [M,N] + bias
template <int MODE>
__global__ __launch_bounds__(256) void gemm_mfma(
    const bf16* __restrict__ A, const bf16* __restrict__ W,
    bf16* __restrict__ qb, bf16* __restrict__ kb, bf16* __restrict__ vb,
    float* __restrict__ outf, const float* __restrict__ bias,
    const int* __restrict__ cmask, const int* __restrict__ cidx,
    int M, int N, int K)
{
    __shared__ __align__(16) short As[128 * 32];
    __shared__ __align__(16) short Bs[128 * 32];

    const int tid  = threadIdx.x;
    const int wave = tid >> 6;
    const int lane = tid & 63;
    const int l15  = lane & 15;
    const int quad = lane >> 4;
    const int wm   = wave >> 1;       // 2x2 wave grid
    const int wn   = wave & 1;
    const int m0   = blockIdx.y * 128;
    const int n0   = blockIdx.x * 128;

    const int ar = tid >> 2;          // 0..63 (row within 64-row chunk)
    const int ac = (tid & 3) * 8;     // 0,8,16,24

    floatx4 acc[4][4];
    #pragma unroll
    for (int mt = 0; mt < 4; mt++)
        #pragma unroll
        for (int nt = 0; nt < 4; nt++)
            #pragma unroll
            for (int r = 0; r < 4; r++) acc[mt][nt][r] = 0.f;

    for (int k0 = 0; k0 < K; k0 += 32) {
        __syncthreads();
        #pragma unroll
        for (int p = 0; p < 2; p++) {
            const bf16* gp = A + (size_t)(m0 + p * 64 + ar) * K + k0 + ac;
            GLD16(gp, &As[(p * 64 + ar) * 32 + ac]);
        }
        #pragma unroll
        for (int p = 0; p < 2; p++) {
            const bf16* gp = W + (size_t)(n0 + p * 64 + ar) * K + k0 + ac;
            GLD16(gp, &Bs[(p * 64 + ar) * 32 + ac]);
        }
        __syncthreads();

        bf16x8 af[4], bfr[4];
        #pragma unroll
        for (int mt = 0; mt < 4; mt++)
            af[mt] = *(const bf16x8*)&As[(wm * 64 + mt * 16 + l15) * 32 + quad * 8];
        #pragma unroll
        for (int nt = 0; nt < 4; nt++)
            bfr[nt] = *(const bf16x8*)&Bs[(wn * 64 + nt * 16 + l15) * 32 + quad * 8];
        #pragma unroll
        for (int mt = 0; mt < 4; mt++)
            #pragma unroll
            for (int nt = 0; nt < 4; nt++)
                acc[mt][nt] = __builtin_amdgcn_mfma_f32_16x16x32_bf16(
                    af[mt], bfr[nt], acc[mt][nt], 0, 0, 0);
    }

    // epilogue: C[row][col], row = m0+wm*64+mt*16+quad*4+r, col = n0+wn*64+nt*16+l15
    if (MODE == 1) {
        #pragma unroll
        for (int mt = 0; mt < 4; mt++)
            #pragma unroll
            for (int r = 0; r < 4; r++) {
                int row = m0 + wm * 64 + mt * 16 + quad * 4 + r;
                #pragma unroll
                for (int nt = 0; nt < 4; nt++) {
                    int col = n0 + wn * 64 + nt * 16 + l15;
                    outf[(size_t)row * N + col] = acc[mt][nt][r] + bias[col];
                }
            }
    } else {
        const int colbase = n0 + wn * 64;          // 64-aligned -> one (which,h)
        const int which   = colbase >> 10;         // 0=q, 1=k, 2=v
        const int hh      = (colbase & (Cc - 1)) >> 6;
        if (which == 2) {
            // V compacted+transposed+swizzled: element (d, c) at
            // head + d*L + (c&~63) + ((((c>>3)&7) ^ (d&7))<<3) + (c&7)
            #pragma unroll
            for (int mt = 0; mt < 4; mt++)
                #pragma unroll
                for (int r = 0; r < 4; r++) {
                    int row = m0 + wm * 64 + mt * 16 + quad * 4 + r;
                    int b = row >> 11, l = row & (Ll - 1);
                    if (cmask[b * Ll + l]) {
                        int c = cidx[b * Ll + l];
                        size_t head = (size_t)(b * Hh + hh) * Dd * Ll;
                        int lbase = (c & ~63) | (c & 7);
                        int lg    = (c >> 3) & 7;
                        #pragma unroll
                        for (int nt = 0; nt < 4; nt++) {
                            int d = nt * 16 + l15;
                            int pos = lbase | ((lg ^ (d & 7)) << 3);
                            vb[head + (size_t)d * Ll + pos] = __float2bfloat16(acc[mt][nt][r]);
                        }
                    }
                }
        } else {
            bf16* dst = which ? kb : qb;
            const float qs = which ? 1.0f : QSCALE;
            const float base0 = __expf(-(float)l15 * INVFREQ_LN);
            const float base1 = __expf(-(float)(l15 + 16) * INVFREQ_LN);
            #pragma unroll
            for (int mt = 0; mt < 4; mt++)
                #pragma unroll
                for (int r = 0; r < 4; r++) {
                    int row = m0 + wm * 64 + mt * 16 + quad * 4 + r;
                    int b = row >> 11, l = row & (Ll - 1);
                    int cm = 1, c = l;
                    if (which == 1) {
                        cm = cmask[b * Ll + l];
                        c  = cidx[b * Ll + l];
                    }
                    if (cm) {
                        size_t rb = ((size_t)(b * Hh + hh) * Ll + c) * Dd;
                        #pragma unroll
                        for (int nt2 = 0; nt2 < 2; nt2++) {
                            float fr = (float)l * (nt2 ? base1 : base0);
                            float sn, cs;
                            __sincosf(fr, &sn, &cs);
                            float x1 = acc[mt][nt2][r];
                            float x2 = acc[mt][nt2 + 2][r];
                            float o1 = (x1 * cs - x2 * sn) * qs;
                            float o2 = (x2 * cs + x1 * sn) * qs;
                            int d1 = nt2 * 16 + l15;
                            int d2 = d1 + 32;
                            if (which == 1) {
                                int sw = c & 7;
                                int a1 = ((((d1 >> 3) ^ sw)) << 3) | (d1 & 7);
                                int a2 = ((((d2 >> 3) ^ sw)) << 3) | (d2 & 7);
                                dst[rb + a1] = __float2bfloat16(o1);
                                dst[rb + a2] = __float2bfloat16(o2);
                            } else {
                                dst[rb + d1] = __float2bfloat16(o1);
                                dst[rb + d2] = __float2bfloat16(o2);
                            }
                        }
                    }
                }
        }
    }
}

// ---------------- Flash attention: compacted keys, GLD16 dbuf, 1 barrier/tile ----------------
// q pre-scaled+roped (linear); k compacted+roped+swizzled; v compacted+transposed+swizzled.
// No mask math: zero-padded tail keys give S=0 -> p=1; denominator corrected by pad count.
// Block = 512 threads = 8 waves; each wave one 16-q subtile (128 q/block).
#define LSTR 72

__global__ __launch_bounds__(512) void attn_mfma(
    const bf16* __restrict__ q, const bf16* __restrict__ k, const bf16* __restrict__ vt,
    const int* __restrict__ valid, bf16* __restrict__ ctx)
{
    __shared__ __align__(16) short Ks[2][64 * 64];
    __shared__ __align__(16) short Vs[2][64 * 64];
    __shared__ __align__(16) short Ps[8][16 * LSTR];

    const int tid  = threadIdx.x;
    const int wave = tid >> 6;
    const int lane = tid & 63;
    const int l15  = lane & 15;
    const int quad = lane >> 4;

    const int bh = blockIdx.x & 31;           // (b*H + h) -> fixed XCD per head
    const int q0 = (blockIdx.x >> 5) << 7;    // 128-query tile start
    const int b  = bh >> 4;
    const int h  = bh & (Hh - 1);

    const int nvalid = valid[b];
    const int ntiles = (nvalid + 63) >> 6;

    const short* qb  = (const short*)(q  + (size_t)bh * Ll * Dd);
    const short* kb  = (const short*)(k  + (size_t)bh * Ll * Dd);
    const short* vtb = (const short*)(vt + (size_t)bh * Dd * Ll);

    // Q fragment: wave's 16 rows (linear layout)
    const int qrow = q0 + wave * 16 + l15;
    bf16x8 qa0 = *(const bf16x8*)(qb + (size_t)qrow * Dd + quad * 8);
    bf16x8 qa1 = *(const bf16x8*)(qb + (size_t)qrow * Dd + 32 + quad * 8);

    // swizzled group offsets (shorts) within a 64-short row, row&7 == l15&7
    const int g0 = ((quad ^ (l15 & 7)) << 3);
    const int g1 = (((quad + 4) ^ (l15 & 7)) << 3);

    // staging pointers: thread covers row tid>>3, group tid&7 of a 64x64 tile
    const short* vgp = vtb + (size_t)(tid >> 3) * Ll + ((tid & 7) << 3);
    short* ksl = &Ks[0][0] + tid * 8;   // lane-linear LDS dest (x8 shorts = 16B)
    short* vsl = &Vs[0][0] + tid * 8;
    const int lbuf = 64 * 64;           // buffer stride in shorts

    floatx4 O[4];
    float l_r = 0.f;
    #pragma unroll
    for (int nt = 0; nt < 4; nt++)
        #pragma unroll
        for (int r = 0; r < 4; r++) O[nt][r] = 0.f;

    // prologue: stage tile 0 into buffer 0
    GLD16(kb + tid * 8, ksl);
    GLD16(vgp, vsl);

    for (int t = 0; t < ntiles; t++) {
        const int cur = t & 1;
        __syncthreads();   // drains this tile's GLDs (vmcnt)
        if (t + 1 < ntiles) {
            const int s1 = (t + 1) << 6;
            GLD16(kb + (size_t)s1 * Dd + tid * 8, ksl + (cur ^ 1) * lbuf);
            GLD16(vgp + s1,                       vsl + (cur ^ 1) * lbuf);
        }

        // ---- S^T = K Q^T: lane holds S[q=l15][key=nt*16+quad*4+r] ----
        const short* Kc = &Ks[cur][0];
        const short* Vc = &Vs[cur][0];
        floatx4 S[4];
        #pragma unroll
        for (int nt = 0; nt < 4; nt++) {
            const short* krow = Kc + (nt * 16 + l15) * 64;
            bf16x8 ka0 = *(const bf16x8*)(krow + g0);
            bf16x8 ka1 = *(const bf16x8*)(krow + g1);
            floatx4 acc; acc[0] = acc[1] = acc[2] = acc[3] = 0.f;
            acc = __builtin_amdgcn_mfma_f32_16x16x32_bf16(ka0, qa0, acc, 0, 0, 0);
            acc = __builtin_amdgcn_mfma_f32_16x16x32_bf16(ka1, qa1, acc, 0, 0, 0);
            S[nt] = acc;
        }

        // ---- softmax (no mask): p = exp(S); packed b64 P-writes ----
        #pragma unroll
        for (int nt = 0; nt < 4; nt++) {
            bf16x4 pw;
            #pragma unroll
            for (int r = 0; r < 4; r++) {
                float p = __expf(S[nt][r]);
                l_r += p;
                pw[r] = f2bf_rn(p);
            }
            *(bf16x4*)&Ps[wave][l15 * LSTR + nt * 16 + quad * 4] = pw;
        }

        // ---- O^T += V^T P^T: A=Vs rows (d, swizzled), B=Ps rows (q) ----
        bf16x8 pb0 = *(const bf16x8*)&Ps[wave][l15 * LSTR + quad * 8];
        bf16x8 pb1 = *(const bf16x8*)&Ps[wave][l15 * LSTR + 32 + quad * 8];
        #pragma unroll
        for (int nt = 0; nt < 4; nt++) {
            const short* vrow = Vc + (nt * 16 + l15) * 64;
            bf16x8 va0 = *(const bf16x8*)(vrow + g0);
            bf16x8 va1 = *(const bf16x8*)(vrow + g1);
            O[nt] = __builtin_amdgcn_mfma_f32_16x16x32_bf16(va0, pb0, O[nt], 0, 0, 0);
            O[nt] = __builtin_amdgcn_mfma_f32_16x16x32_bf16(va1, pb1, O[nt], 0, 0, 0);
        }
    }

    // ---- row-sum (quads hold same q) + pad correction ----
    float l = l_r;
    l += __shfl_xor(l, 16);
    l += __shfl_xor(l, 32);
    l -= (float)((ntiles << 6) - nvalid);   // each zero-pad key contributed exp(0)=1
    const float inv = 1.0f / l;

    // ---- write ctx: lane holds O[q=l15][d=nt*16+quad*4+r] -> b64 stores ----
    {
        int row = q0 + wave * 16 + l15;
        short* cp = (short*)ctx + ((size_t)(b * Ll + row)) * Cc + h * Dd;
        #pragma unroll
        for (int nt = 0; nt < 4; nt++) {
            bf16x4 ov;
            #pragma unroll
            for (int r = 0; r < 4; r++) ov[r] = f2bf_rn(O[nt][r] * inv);
            *(bf16x4*)&cp[nt * 16 + quad * 4] = ov;
        }
    }
}

extern "C" void kernel_launch(void* const* d_in, const int* in_sizes, int n_in,
                              void* d_out, int out_size, void* d_ws, size_t ws_size,
                              hipStream_t stream) {
    const float* x    = (const float*)d_in[0];
    const int*   mask = (const int*)d_in[1];
    const float* Wq   = (const float*)d_in[2];
    const float* Wk   = (const float*)d_in[3];
    const float* Wv   = (const float*)d_in[4];
    const float* Wo   = (const float*)d_in[5];
    const float* bo   = (const float*)d_in[6];
    float* out = (float*)d_out;

    const size_t per = (size_t)Bb * Hh * Ll * Dd;   // 4 Mi elements
    bf16* qbuf = (bf16*)d_ws;
    bf16* kbuf = qbuf + per;            // compacted + swizzled
    bf16* vbuf = kbuf + per;            // compacted + transposed [B,H,D,L'] + swizzled
    bf16* xb   = vbuf + per;            // also used as ctx after x is dead
    bf16* wqkv = xb + per;              // [3072, 1024]
    bf16* wob  = wqkv + (size_t)3 * Cc * Cc;
    int*  cidx   = (int*)(wob + (size_t)Cc * Cc);
    int*  cvalid = cidx + Bb * Ll;
    bf16* ctx  = xb;

    const int M = Bb * Ll;   // 4096

    convert_bf16<<<(Bb*Ll*Cc/8 + 4*Cc*Cc/8) / 256, 256, 0, stream>>>(
        x, Wq, Wk, Wv, Wo, xb, wqkv, wob);

    mask_scan<<<Bb, 256, 0, stream>>>(mask, cidx, cvalid);

    // zero K/V so the padded tail tile reads as exact zeros
    hipMemsetAsync(kbuf, 0, 2 * per * sizeof(bf16), stream);

    // fused QKV projection + RoPE + Q-scale + K/V compaction/swizzle + V-transpose
    dim3 gQKV(3 * Cc / 128, M / 128);
    gemm_mfma<0><<<gQKV, 256, 0, stream>>>(xb, wqkv, qbuf, kbuf, vbuf,
                                           nullptr, nullptr, mask, cidx, M, 3 * Cc, Cc);

    attn_mfma<<<Bb * Hh * (Ll / 128), 512, 0, stream>>>(qbuf, kbuf, vbuf, cvalid, ctx);

    // output projection: [4096, 1024] fp32 + bias
    dim3 gOut(Cc / 128, M / 128);
    gemm_mfma<1><<<gOut, 256, 0, stream>>>(ctx, wob, nullptr, nullptr, nullptr,
                                           out, bo, nullptr, nullptr, M, Cc, Cc);
}

// Round 12
// 180.684 us; speedup vs baseline: 28.9774x; 1.0595x over previous
//
#include <hip/hip_runtime.h>
#include <hip/hip_bf16.h>

typedef __hip_bfloat16 bf16;
typedef short bf16x8 __attribute__((ext_vector_type(8)));
typedef short bf16x4 __attribute__((ext_vector_type(4)));
typedef float floatx4 __attribute__((ext_vector_type(4)));

#define Bb 2
#define Ll 2048
#define Cc 1024
#define Hh 16
#define Dd 64
// ln(50000)/32
#define INVFREQ_LN 0.3381180763f
// plain 1/sqrt(D) folded into Q; softmax uses __expf (natural)
#define QSCALE 0.125f
#define NCONV 4096

#define GLD16(gp, lp) __builtin_amdgcn_global_load_lds( \
    (const __attribute__((address_space(1))) void*)(gp), \
    (__attribute__((address_space(3))) void*)(lp), 16, 0, 0)

__device__ inline short f2bf(float f) {
    __hip_bfloat16 h = __float2bfloat16(f);
    return *reinterpret_cast<short*>(&h);
}
// fast round-to-nearest bf16; fine for finite values
__device__ inline short f2bf_rn(float f) {
    return (short)((__float_as_uint(f) + 0x8000u) >> 16);
}

// ---------------- convert fp32 -> bf16 workspace + fused per-batch mask scan ----------------
__global__ __launch_bounds__(256) void convert_scan(
    const float* __restrict__ x, const float* __restrict__ wq,
    const float* __restrict__ wk, const float* __restrict__ wv,
    const float* __restrict__ wo,
    bf16* __restrict__ xb, bf16* __restrict__ wqkv, bf16* __restrict__ wob,
    const int* __restrict__ mask, int* __restrict__ cidx, int* __restrict__ valid)
{
    if (blockIdx.x >= NCONV) {
        // ---- mask scan for batch b ----
        const int b   = blockIdx.x - NCONV;
        const int tid = threadIdx.x;
        const int base = b * Ll + tid * 8;
        int m[8]; int s = 0;
        #pragma unroll
        for (int i = 0; i < 8; i++) { m[i] = mask[base + i] ? 1 : 0; s += m[i]; }
        const int lane = tid & 63;
        int xx = s;
        #pragma unroll
        for (int off = 1; off < 64; off <<= 1) {
            int y = __shfl_up(xx, off);
            if (lane >= off) xx += y;
        }
        __shared__ int wtot[4];
        if (lane == 63) wtot[tid >> 6] = xx;
        __syncthreads();
        int wbase = 0;
        const int w = tid >> 6;
        #pragma unroll
        for (int i = 0; i < 4; i++) if (i < w) wbase += wtot[i];
        int run = wbase + (xx - s);
        #pragma unroll
        for (int i = 0; i < 8; i++) { cidx[base + i] = run; run += m[i]; }
        if (tid == 255) valid[b] = run;
        return;
    }

    const int XN = (Bb * Ll * Cc) / 8;   // 524288
    const int WN = (Cc * Cc) / 8;        // 131072
    int i = blockIdx.x * 256 + threadIdx.x;
    const float* src; bf16* dst;
    if (i < XN)               { src = x  + (size_t)i * 8;                 dst = xb   + (size_t)i * 8; }
    else if (i < XN + WN)     { int j = i - XN;        src = wq + (size_t)j * 8; dst = wqkv + (size_t)j * 8; }
    else if (i < XN + 2*WN)   { int j = i - XN - WN;   src = wk + (size_t)j * 8; dst = wqkv + (size_t)Cc*Cc     + (size_t)j * 8; }
    else if (i < XN + 3*WN)   { int j = i - XN - 2*WN; src = wv + (size_t)j * 8; dst = wqkv + (size_t)Cc*Cc*2   + (size_t)j * 8; }
    else                      { int j = i - XN - 3*WN; src = wo + (size_t)j * 8; dst = wob  + (size_t)j * 8; }
    float4 a = *reinterpret_cast<const float4*>(src);
    float4 b = *reinterpret_cast<const float4*>(src + 4);
    float vv[8] = {a.x, a.y, a.z, a.w, b.x, b.y, b.z, b.w};
    bf16x8 o;
    #pragma unroll
    for (int t = 0; t < 8; t++) o[t] = f2bf(vv[t]);
    *reinterpret_cast<bf16x8*>(dst) = o;
}

// ---------------- MFMA GEMM: C = A[M,K] . W[N,K]^T, all bf16, dbuf K-loop ----------------
// MODE 0: N=3072 fused QKV. Epilogue: RoPE+scale on q (linear layout);
//         K/V written COMPACTED by cidx (masked keys dropped), K with XOR-swizzled
//         16B groups; V transposed [B,H,D,L'] with per-64-chunk XOR swizzle by (d&7).
// MODE 1: N=1024, out fp32 [M,N] + bias
template <int MODE>
__global__ __launch_bounds__(256) void gemm_mfma(
    const bf16* __restrict__ A, const bf16* __restrict__ W,
    bf16* __restrict__ qb, bf16* __restrict__ kb, bf16* __restrict__ vb,
    float* __restrict__ outf, const float* __restrict__ bias,
    const int* __restrict__ cmask, const int* __restrict__ cidx,
    int M, int N, int K)
{
    __shared__ __align__(16) short As[2][128 * 32];
    __shared__ __align__(16) short Bs[2][128 * 32];

    const int tid  = threadIdx.x;
    const int wave = tid >> 6;
    const int lane = tid & 63;
    const int l15  = lane & 15;
    const int quad = lane >> 4;
    const int wm   = wave >> 1;       // 2x2 wave grid
    const int wn   = wave & 1;
    const int m0   = blockIdx.y * 128;
    const int n0   = blockIdx.x * 128;

    const int ar = tid >> 2;          // 0..63 (row within 64-row chunk)
    const int ac = (tid & 3) * 8;     // 0,8,16,24

    floatx4 acc[4][4];
    #pragma unroll
    for (int mt = 0; mt < 4; mt++)
        #pragma unroll
        for (int nt = 0; nt < 4; nt++)
            #pragma unroll
            for (int r = 0; r < 4; r++) acc[mt][nt][r] = 0.f;

    // prologue: stage k0=0 into buffer 0
    #pragma unroll
    for (int p = 0; p < 2; p++) {
        GLD16(A + (size_t)(m0 + p * 64 + ar) * K + ac, &As[0][(p * 64 + ar) * 32 + ac]);
        GLD16(W + (size_t)(n0 + p * 64 + ar) * K + ac, &Bs[0][(p * 64 + ar) * 32 + ac]);
    }

    for (int k0 = 0; k0 < K; k0 += 32) {
        const int cur = (k0 >> 5) & 1;
        __syncthreads();   // drains this tile's GLDs
        if (k0 + 32 < K) {
            #pragma unroll
            for (int p = 0; p < 2; p++) {
                GLD16(A + (size_t)(m0 + p * 64 + ar) * K + k0 + 32 + ac,
                      &As[cur ^ 1][(p * 64 + ar) * 32 + ac]);
                GLD16(W + (size_t)(n0 + p * 64 + ar) * K + k0 + 32 + ac,
                      &Bs[cur ^ 1][(p * 64 + ar) * 32 + ac]);
            }
        }

        bf16x8 af[4], bfr[4];
        #pragma unroll
        for (int mt = 0; mt < 4; mt++)
            af[mt] = *(const bf16x8*)&As[cur][(wm * 64 + mt * 16 + l15) * 32 + quad * 8];
        #pragma unroll
        for (int nt = 0; nt < 4; nt++)
            bfr[nt] = *(const bf16x8*)&Bs[cur][(wn * 64 + nt * 16 + l15) * 32 + quad * 8];
        #pragma unroll
        for (int mt = 0; mt < 4; mt++)
            #pragma unroll
            for (int nt = 0; nt < 4; nt++)
                acc[mt][nt] = __builtin_amdgcn_mfma_f32_16x16x32_bf16(
                    af[mt], bfr[nt], acc[mt][nt], 0, 0, 0);
    }

    // epilogue: C[row][col], row = m0+wm*64+mt*16+quad*4+r, col = n0+wn*64+nt*16+l15
    if (MODE == 1) {
        #pragma unroll
        for (int mt = 0; mt < 4; mt++)
            #pragma unroll
            for (int r = 0; r < 4; r++) {
                int row = m0 + wm * 64 + mt * 16 + quad * 4 + r;
                #pragma unroll
                for (int nt = 0; nt < 4; nt++) {
                    int col = n0 + wn * 64 + nt * 16 + l15;
                    outf[(size_t)row * N + col] = acc[mt][nt][r] + bias[col];
                }
            }
    } else {
        const int colbase = n0 + wn * 64;          // 64-aligned -> one (which,h)
        const int which   = colbase >> 10;         // 0=q, 1=k, 2=v
        const int hh      = (colbase & (Cc - 1)) >> 6;
        if (which == 2) {
            // V compacted+transposed+swizzled: element (d, c) at
            // head + d*L + (c&~63) + ((((c>>3)&7) ^ (d&7))<<3) + (c&7)
            #pragma unroll
            for (int mt = 0; mt < 4; mt++)
                #pragma unroll
                for (int r = 0; r < 4; r++) {
                    int row = m0 + wm * 64 + mt * 16 + quad * 4 + r;
                    int b = row >> 11, l = row & (Ll - 1);
                    if (cmask[b * Ll + l]) {
                        int c = cidx[b * Ll + l];
                        size_t head = (size_t)(b * Hh + hh) * Dd * Ll;
                        int lbase = (c & ~63) | (c & 7);
                        int lg    = (c >> 3) & 7;
                        #pragma unroll
                        for (int nt = 0; nt < 4; nt++) {
                            int d = nt * 16 + l15;
                            int pos = lbase | ((lg ^ (d & 7)) << 3);
                            vb[head + (size_t)d * Ll + pos] = __float2bfloat16(acc[mt][nt][r]);
                        }
                    }
                }
        } else {
            bf16* dst = which ? kb : qb;
            const float qs = which ? 1.0f : QSCALE;
            const float base0 = __expf(-(float)l15 * INVFREQ_LN);
            const float base1 = __expf(-(float)(l15 + 16) * INVFREQ_LN);
            #pragma unroll
            for (int mt = 0; mt < 4; mt++)
                #pragma unroll
                for (int r = 0; r < 4; r++) {
                    int row = m0 + wm * 64 + mt * 16 + quad * 4 + r;
                    int b = row >> 11, l = row & (Ll - 1);
                    int cm = 1, c = l;
                    if (which == 1) {
                        cm = cmask[b * Ll + l];
                        c  = cidx[b * Ll + l];
                    }
                    if (cm) {
                        size_t rb = ((size_t)(b * Hh + hh) * Ll + c) * Dd;
                        #pragma unroll
                        for (int nt2 = 0; nt2 < 2; nt2++) {
                            float fr = (float)l * (nt2 ? base1 : base0);
                            float sn, cs;
                            __sincosf(fr, &sn, &cs);
                            float x1 = acc[mt][nt2][r];
                            float x2 = acc[mt][nt2 + 2][r];
                            float o1 = (x1 * cs - x2 * sn) * qs;
                            float o2 = (x2 * cs + x1 * sn) * qs;
                            int d1 = nt2 * 16 + l15;
                            int d2 = d1 + 32;
                            if (which == 1) {
                                int sw = c & 7;
                                int a1 = ((((d1 >> 3) ^ sw)) << 3) | (d1 & 7);
                                int a2 = ((((d2 >> 3) ^ sw)) << 3) | (d2 & 7);
                                dst[rb + a1] = __float2bfloat16(o1);
                                dst[rb + a2] = __float2bfloat16(o2);
                            } else {
                                dst[rb + d1] = __float2bfloat16(o1);
                                dst[rb + d2] = __float2bfloat16(o2);
                            }
                        }
                    }
                }
        }
    }
}

// ---------------- Flash attention: compacted keys, GLD16 dbuf, 1 barrier/tile ----------------
// q pre-scaled+roped (linear); k compacted+roped+swizzled; v compacted+transposed+swizzled.
// Tail tile masked by key index (p=0 for key >= nvalid) -> no memset, no pad correction.
// Block = 512 threads = 8 waves; each wave one 16-q subtile (128 q/block).
#define LSTR 72

__global__ __launch_bounds__(512) void attn_mfma(
    const bf16* __restrict__ q, const bf16* __restrict__ k, const bf16* __restrict__ vt,
    const int* __restrict__ valid, bf16* __restrict__ ctx)
{
    __shared__ __align__(16) short Ks[2][64 * 64];
    __shared__ __align__(16) short Vs[2][64 * 64];
    __shared__ __align__(16) short Ps[8][16 * LSTR];

    const int tid  = threadIdx.x;
    const int wave = tid >> 6;
    const int lane = tid & 63;
    const int l15  = lane & 15;
    const int quad = lane >> 4;

    const int bh = blockIdx.x & 31;           // (b*H + h) -> fixed XCD per head
    const int q0 = (blockIdx.x >> 5) << 7;    // 128-query tile start
    const int b  = bh >> 4;
    const int h  = bh & (Hh - 1);

    const int nvalid = valid[b];
    const int ntiles = (nvalid + 63) >> 6;

    const short* qb  = (const short*)(q  + (size_t)bh * Ll * Dd);
    const short* kb  = (const short*)(k  + (size_t)bh * Ll * Dd);
    const short* vtb = (const short*)(vt + (size_t)bh * Dd * Ll);

    // Q fragment: wave's 16 rows (linear layout)
    const int qrow = q0 + wave * 16 + l15;
    bf16x8 qa0 = *(const bf16x8*)(qb + (size_t)qrow * Dd + quad * 8);
    bf16x8 qa1 = *(const bf16x8*)(qb + (size_t)qrow * Dd + 32 + quad * 8);

    // swizzled group offsets (shorts) within a 64-short row, row&7 == l15&7
    const int g0 = ((quad ^ (l15 & 7)) << 3);
    const int g1 = (((quad + 4) ^ (l15 & 7)) << 3);

    // staging pointers: thread covers row tid>>3, group tid&7 of a 64x64 tile
    const short* vgp = vtb + (size_t)(tid >> 3) * Ll + ((tid & 7) << 3);
    short* ksl = &Ks[0][0] + tid * 8;   // lane-linear LDS dest (x8 shorts = 16B)
    short* vsl = &Vs[0][0] + tid * 8;
    const int lbuf = 64 * 64;           // buffer stride in shorts

    floatx4 O[4];
    float l_r = 0.f;
    #pragma unroll
    for (int nt = 0; nt < 4; nt++)
        #pragma unroll
        for (int r = 0; r < 4; r++) O[nt][r] = 0.f;

    // prologue: stage tile 0 into buffer 0
    GLD16(kb + tid * 8, ksl);
    GLD16(vgp, vsl);

    for (int t = 0; t < ntiles; t++) {
        const int cur = t & 1;
        __syncthreads();   // drains this tile's GLDs (vmcnt)
        if (t + 1 < ntiles) {
            const int s1 = (t + 1) << 6;
            GLD16(kb + (size_t)s1 * Dd + tid * 8, ksl + (cur ^ 1) * lbuf);
            GLD16(vgp + s1,                       vsl + (cur ^ 1) * lbuf);
        }

        // ---- S^T = K Q^T: lane holds S[q=l15][key=nt*16+quad*4+r] ----
        const short* Kc = &Ks[cur][0];
        const short* Vc = &Vs[cur][0];
        floatx4 S[4];
        #pragma unroll
        for (int nt = 0; nt < 4; nt++) {
            const short* krow = Kc + (nt * 16 + l15) * 64;
            bf16x8 ka0 = *(const bf16x8*)(krow + g0);
            bf16x8 ka1 = *(const bf16x8*)(krow + g1);
            floatx4 acc; acc[0] = acc[1] = acc[2] = acc[3] = 0.f;
            acc = __builtin_amdgcn_mfma_f32_16x16x32_bf16(ka0, qa0, acc, 0, 0, 0);
            acc = __builtin_amdgcn_mfma_f32_16x16x32_bf16(ka1, qa1, acc, 0, 0, 0);
            S[nt] = acc;
        }

        // ---- softmax: p = exp(S); tail tile masks key >= nvalid ----
        if (t + 1 < ntiles) {
            #pragma unroll
            for (int nt = 0; nt < 4; nt++) {
                bf16x4 pw;
                #pragma unroll
                for (int r = 0; r < 4; r++) {
                    float p = __expf(S[nt][r]);
                    l_r += p;
                    pw[r] = f2bf_rn(p);
                }
                *(bf16x4*)&Ps[wave][l15 * LSTR + nt * 16 + quad * 4] = pw;
            }
        } else {
            const int kbase = (t << 6) + quad * 4;
            #pragma unroll
            for (int nt = 0; nt < 4; nt++) {
                bf16x4 pw;
                #pragma unroll
                for (int r = 0; r < 4; r++) {
                    float p = (kbase + nt * 16 + r < nvalid) ? __expf(S[nt][r]) : 0.f;
                    l_r += p;
                    pw[r] = f2bf_rn(p);
                }
                *(bf16x4*)&Ps[wave][l15 * LSTR + nt * 16 + quad * 4] = pw;
            }
        }

        // ---- O^T += V^T P^T: A=Vs rows (d, swizzled), B=Ps rows (q) ----
        bf16x8 pb0 = *(const bf16x8*)&Ps[wave][l15 * LSTR + quad * 8];
        bf16x8 pb1 = *(const bf16x8*)&Ps[wave][l15 * LSTR + 32 + quad * 8];
        #pragma unroll
        for (int nt = 0; nt < 4; nt++) {
            const short* vrow = Vc + (nt * 16 + l15) * 64;
            bf16x8 va0 = *(const bf16x8*)(vrow + g0);
            bf16x8 va1 = *(const bf16x8*)(vrow + g1);
            O[nt] = __builtin_amdgcn_mfma_f32_16x16x32_bf16(va0, pb0, O[nt], 0, 0, 0);
            O[nt] = __builtin_amdgcn_mfma_f32_16x16x32_bf16(va1, pb1, O[nt], 0, 0, 0);
        }
    }

    // ---- row-sum (quads hold same q) ----
    float l = l_r;
    l += __shfl_xor(l, 16);
    l += __shfl_xor(l, 32);
    const float inv = 1.0f / l;

    // ---- write ctx: lane holds O[q=l15][d=nt*16+quad*4+r] -> b64 stores ----
    {
        int row = q0 + wave * 16 + l15;
        short* cp = (short*)ctx + ((size_t)(b * Ll + row)) * Cc + h * Dd;
        #pragma unroll
        for (int nt = 0; nt < 4; nt++) {
            bf16x4 ov;
            #pragma unroll
            for (int r = 0; r < 4; r++) ov[r] = f2bf_rn(O[nt][r] * inv);
            *(bf16x4*)&cp[nt * 16 + quad * 4] = ov;
        }
    }
}

extern "C" void kernel_launch(void* const* d_in, const int* in_sizes, int n_in,
                              void* d_out, int out_size, void* d_ws, size_t ws_size,
                              hipStream_t stream) {
    const float* x    = (const float*)d_in[0];
    const int*   mask = (const int*)d_in[1];
    const float* Wq   = (const float*)d_in[2];
    const float* Wk   = (const float*)d_in[3];
    const float* Wv   = (const float*)d_in[4];
    const float* Wo   = (const float*)d_in[5];
    const float* bo   = (const float*)d_in[6];
    float* out = (float*)d_out;

    const size_t per = (size_t)Bb * Hh * Ll * Dd;   // 4 Mi elements
    bf16* qbuf = (bf16*)d_ws;
    bf16* kbuf = qbuf + per;            // compacted + swizzled
    bf16* vbuf = kbuf + per;            // compacted + transposed [B,H,D,L'] + swizzled
    bf16* xb   = vbuf + per;            // also used as ctx after x is dead
    bf16* wqkv = xb + per;              // [3072, 1024]
    bf16* wob  = wqkv + (size_t)3 * Cc * Cc;
    int*  cidx   = (int*)(wob + (size_t)Cc * Cc);
    int*  cvalid = cidx + Bb * Ll;
    bf16* ctx  = xb;

    const int M = Bb * Ll;   // 4096

    convert_scan<<<NCONV + Bb, 256, 0, stream>>>(
        x, Wq, Wk, Wv, Wo, xb, wqkv, wob, mask, cidx, cvalid);

    // fused QKV projection + RoPE + Q-scale + K/V compaction/swizzle + V-transpose
    dim3 gQKV(3 * Cc / 128, M / 128);
    gemm_mfma<0><<<gQKV, 256, 0, stream>>>(xb, wqkv, qbuf, kbuf, vbuf,
                                           nullptr, nullptr, mask, cidx, M, 3 * Cc, Cc);

    attn_mfma<<<Bb * Hh * (Ll / 128), 512, 0, stream>>>(qbuf, kbuf, vbuf, cvalid, ctx);

    // output projection: [4096, 1024] fp32 + bias
    dim3 gOut(Cc / 128, M / 128);
    gemm_mfma<1><<<gOut, 256, 0, stream>>>(ctx, wob, nullptr, nullptr, nullptr,
                                           out, bo, nullptr, nullptr, M, Cc, Cc);
}